// Round 4
// baseline (2780.417 us; speedup 1.0000x reference)
//
#include <hip/hip_runtime.h>
#include <hip/hip_bf16.h>

// Problem constants (fixed by reference)
#define NN 8192
#define NMASK 8191
#define IND 3000
#define INDP 3008   // padded K for W1t rows: 3008*2B = 6016 bytes, 16B-aligned rows
#define H1 256
#define OUTD 64

typedef __bf16 bf16x8 __attribute__((ext_vector_type(8)));
typedef float floatx4 __attribute__((ext_vector_type(4)));

typedef const __attribute__((address_space(1))) void GV;
typedef __attribute__((address_space(3))) void LV;

__device__ __forceinline__ unsigned short f2b(float f) {
    __hip_bfloat16 h = __float2bfloat16(f);
    unsigned short u;
    __builtin_memcpy(&u, &h, 2);
    return u;
}

// ---------------- ws-size probe ----------------

__global__ void k_probe(float code, float* out) {
    if (threadIdx.x == 0 && blockIdx.x == 0) out[0] = code;
}

// ---------------- DIAGNOSTIC: stamp + spin (attribution via rocprof top-5) ----------------
// k_stamp records s_memrealtime (100 MHz constant-rate) into ws.
// k_spin busy-waits 180us + 4x(stage span) so the five spins occupy the whole
// rocprof top-5 and their dur_us encodes per-stage wall time:
//   T_stage = (dur_spin - C)/4,  C ~ 180us, identified by _ord order.

__global__ void k_stamp(unsigned long long* __restrict__ buf, int idx) {
    if (threadIdx.x == 0 && blockIdx.x == 0)
        buf[idx] = __builtin_amdgcn_s_memrealtime();
}

__global__ void k_spin(const unsigned long long* __restrict__ buf, int idx) {
    if (blockIdx.x != 0) return;
    unsigned long long a = buf[idx], b = buf[idx + 1];
    unsigned long long d = (b > a) ? (b - a) : 0ull;
    if (d > 100000000ull) d = 0ull;                 // garbage guard
    unsigned long long target = 18000ull + 4ull * d;  // 180us + 4x span @100MHz
    if (target > 500000ull) target = 500000ull;       // 5ms clamp
    unsigned long long t0 = __builtin_amdgcn_s_memrealtime();
    while (__builtin_amdgcn_s_memrealtime() - t0 < target) {
        asm volatile("" ::: "memory");
    }
}

// ---------------- fused pre-pass: detect widths, zero deg, zero W1t pad, transposes ----------------

__global__ void k_pre(const unsigned* __restrict__ eraw, const unsigned* __restrict__ praw,
                      int* __restrict__ flags, int* __restrict__ deg,
                      const float* __restrict__ W1, const float* __restrict__ W2,
                      __hip_bfloat16* __restrict__ W1t, __hip_bfloat16* __restrict__ W2t) {
    int b = blockIdx.x;
    int t = threadIdx.x;
    if (b < 2) {
        const unsigned* r = (b == 0) ? eraw : praw;
        __shared__ int cnt;
        if (t == 0) cnt = 0;
        __syncthreads();
        int z = 0;
        for (int k = t; k < 2048; k += 256)
            if (r[2 * k + 1] == 0u) z++;
        atomicAdd(&cnt, z);
        __syncthreads();
        if (t == 0) flags[b] = (cnt > 1024) ? 1 : 0;
    } else if (b < 10) {
#pragma unroll
        for (int u = 0; u < 4; ++u) deg[(b - 2) * 1024 + u * 256 + t] = 0;
    } else if (b < 12) {
        int idx = (b - 10) * 256 + t;  // 0..511, each covers 4 pad elems
#pragma unroll
        for (int u = 0; u < 4; ++u) {
            int k = idx * 4 + u;       // 0..2047
            int c = k >> 3;
            int r = 3000 + (k & 7);
            W1t[(size_t)c * INDP + r] = __float2bfloat16(0.f);
        }
    } else {
        int idx = (b - 12) * 256 + t;
        if (idx < IND * H1) {
            int r = idx / H1, c = idx % H1;
            W1t[(size_t)c * INDP + r] = __float2bfloat16(W1[idx]);
        } else {
            int j = idx - IND * H1;
            if (j < H1 * OUTD) {
                int r = j / OUTD, c = j % OUTD;
                W2t[(size_t)c * H1 + r] = __float2bfloat16(W2[j]);
            }
        }
    }
}

// ---------------- normalize eidx + perm AND degree accumulation, one pass ----------------

__global__ void k_prep(const unsigned* __restrict__ eraw, const unsigned* __restrict__ praw,
                       const int* __restrict__ flags, int* __restrict__ eidx32,
                       int* __restrict__ perm32, int* __restrict__ deg, int E, int n) {
    int i = blockIdx.x * blockDim.x + threadIdx.x;
    if (i < 2 * E) {
        unsigned v = flags[0] ? eraw[2 * (size_t)i] : eraw[i];
        int x = (int)(v & (unsigned)NMASK);
        eidx32[i] = x;
        if (i >= E) atomicAdd(&deg[x], 1);  // dst half drives in-degree
    } else {
        int j = i - 2 * E;
        if (j < n) {
            unsigned v = flags[1] ? praw[2 * (size_t)j] : praw[j];
            perm32[j] = (int)(v & (unsigned)NMASK);
        }
    }
}

// ---------------- CSR scan ----------------

__global__ __launch_bounds__(1024) void k_scan(const int* __restrict__ deg,
                                               int* __restrict__ row_ptr,
                                               int* __restrict__ cursor,
                                               float* __restrict__ dinv, int n) {
    __shared__ int sums[1024];
    int t = threadIdx.x;
    int per = n / 1024;  // 8
    int base = t * per;
    int s = 0;
    for (int u = 0; u < per; ++u) s += deg[base + u];
    sums[t] = s;
    __syncthreads();
    for (int off = 1; off < 1024; off <<= 1) {
        int v = (t >= off) ? sums[t - off] : 0;
        __syncthreads();
        sums[t] += v;
        __syncthreads();
    }
    int run = (t == 0) ? 0 : sums[t - 1];
    for (int u = 0; u < per; ++u) {
        int i = base + u;
        row_ptr[i] = run;
        cursor[i] = run;
        int d = deg[i];
        dinv[i] = rsqrtf((float)(1 + d));
        run += d;
    }
    if (t == 1023) row_ptr[n] = run;
}

__global__ void k_scatter(const int* __restrict__ src, const int* __restrict__ dst,
                          int* __restrict__ cursor, int* __restrict__ col, int E) {
    int e = blockIdx.x * blockDim.x + threadIdx.x;
    if (e < E) {
        int d = dst[e];
        int p = atomicAdd(&cursor[d], 1);
        if (p >= 0 && p < E) col[p] = src[e];
    }
}

// ---------------- GEMM1: xw1[8192][256] = gene(fp32) @ W1 ----------------

__global__ __launch_bounds__(256) void k_gemm1(const float* __restrict__ A,
                                               const __hip_bfloat16* __restrict__ Bt,
                                               float* __restrict__ C) {
    __shared__ __align__(16) unsigned short As[64 * 72];
    __shared__ __align__(16) unsigned short Bs[64 * 72];
    int t = threadIdx.x;
    int n0 = blockIdx.x * 64;
    int m0 = blockIdx.y * 64;
    int lane = t & 63;
    int w = t >> 6;
    int srow = t >> 2;
    int schunk = (t & 3) * 16;
    const float* Arow = A + (size_t)(m0 + srow) * IND + schunk;
    const unsigned short* Brow = (const unsigned short*)Bt + (size_t)(n0 + srow) * INDP + schunk;

    floatx4 acc0 = {0.f, 0.f, 0.f, 0.f}, acc1 = acc0, acc2 = acc0, acc3 = acc0;
    int msub = w * 16;
    int arow = msub + (lane & 15);
    int koff = (lane >> 4) * 8;
    int nlo = lane & 15;

    float4 pa0, pa1, pa2, pa3;
    uint4 pb0, pb1;
    auto load_tile = [&](int k0) {
        float4 z4 = make_float4(0.f, 0.f, 0.f, 0.f);
        uint4 zu = make_uint4(0u, 0u, 0u, 0u);
        pa0 = z4; pa1 = z4; pa2 = z4; pa3 = z4; pb0 = zu; pb1 = zu;
        int kk = k0 + schunk;
        if (kk < IND) {
            const float* ap = Arow + k0;
            pa0 = *reinterpret_cast<const float4*>(ap);
            pa1 = *reinterpret_cast<const float4*>(ap + 4);
            pb0 = *reinterpret_cast<const uint4*>(Brow + k0);
        }
        if (kk + 8 < IND) {
            const float* ap = Arow + k0 + 8;
            pa2 = *reinterpret_cast<const float4*>(ap);
            pa3 = *reinterpret_cast<const float4*>(ap + 4);
            pb1 = *reinterpret_cast<const uint4*>(Brow + k0 + 8);
        }
    };
    load_tile(0);
    for (int k0 = 0; k0 < IND; k0 += 64) {
        uint4 av0, av1, bv0 = pb0, bv1 = pb1;
        {
            unsigned short t8[8] = {f2b(pa0.x), f2b(pa0.y), f2b(pa0.z), f2b(pa0.w),
                                    f2b(pa1.x), f2b(pa1.y), f2b(pa1.z), f2b(pa1.w)};
            __builtin_memcpy(&av0, t8, 16);
        }
        {
            unsigned short t8[8] = {f2b(pa2.x), f2b(pa2.y), f2b(pa2.z), f2b(pa2.w),
                                    f2b(pa3.x), f2b(pa3.y), f2b(pa3.z), f2b(pa3.w)};
            __builtin_memcpy(&av1, t8, 16);
        }
        __syncthreads();
        *reinterpret_cast<uint4*>(&As[srow * 72 + schunk]) = av0;
        *reinterpret_cast<uint4*>(&As[srow * 72 + schunk + 8]) = av1;
        *reinterpret_cast<uint4*>(&Bs[srow * 72 + schunk]) = bv0;
        *reinterpret_cast<uint4*>(&Bs[srow * 72 + schunk + 8]) = bv1;
        __syncthreads();
        if (k0 + 64 < IND) load_tile(k0 + 64);
#pragma unroll
        for (int ks = 0; ks < 64; ks += 32) {
            bf16x8 af = *reinterpret_cast<const bf16x8*>(&As[arow * 72 + ks + koff]);
            bf16x8 b0 = *reinterpret_cast<const bf16x8*>(&Bs[(0 + nlo) * 72 + ks + koff]);
            bf16x8 b1 = *reinterpret_cast<const bf16x8*>(&Bs[(16 + nlo) * 72 + ks + koff]);
            bf16x8 b2 = *reinterpret_cast<const bf16x8*>(&Bs[(32 + nlo) * 72 + ks + koff]);
            bf16x8 b3 = *reinterpret_cast<const bf16x8*>(&Bs[(48 + nlo) * 72 + ks + koff]);
            acc0 = __builtin_amdgcn_mfma_f32_16x16x32_bf16(af, b0, acc0, 0, 0, 0);
            acc1 = __builtin_amdgcn_mfma_f32_16x16x32_bf16(af, b1, acc1, 0, 0, 0);
            acc2 = __builtin_amdgcn_mfma_f32_16x16x32_bf16(af, b2, acc2, 0, 0, 0);
            acc3 = __builtin_amdgcn_mfma_f32_16x16x32_bf16(af, b3, acc3, 0, 0, 0);
        }
    }
    int crow = msub + (lane >> 4) * 4;
    int ccol = lane & 15;
    floatx4 accs[4] = {acc0, acc1, acc2, acc3};
#pragma unroll
    for (int j = 0; j < 4; ++j) {
#pragma unroll
        for (int r = 0; r < 4; ++r) {
            C[(size_t)(m0 + crow + r) * H1 + (n0 + j * 16 + ccol)] = accs[j][r];
        }
    }
}

// ---------------- GEMM2: hw_all = h_all(bf16) @ W2, BM=64 BN=64 BK=32, reg-prefetch ----------------

__global__ __launch_bounds__(256) void k_gemm2(const __hip_bfloat16* __restrict__ A,
                                               const __hip_bfloat16* __restrict__ Bt,
                                               float* __restrict__ C,
                                               int M, int N, int K) {
    __shared__ __align__(16) unsigned short As[64 * 40];
    __shared__ __align__(16) unsigned short Bs[64 * 40];
    int t = threadIdx.x;
    int m0 = blockIdx.x * 64;
    int n0 = blockIdx.y * 64;
    int lane = t & 63;
    int w = t >> 6;
    int srow = t >> 2;
    int schunk = (t & 3) * 8;
    size_t aoff = (size_t)(m0 + srow) * K + schunk;
    const unsigned short* Brow = (const unsigned short*)Bt + (size_t)(n0 + srow) * K + schunk;

    floatx4 acc0 = {0.f, 0.f, 0.f, 0.f}, acc1 = acc0, acc2 = acc0, acc3 = acc0;
    int msub = w * 16;
    int arow = msub + (lane & 15);
    int koff = (lane >> 4) * 8;
    int nlo = lane & 15;

    uint4 pa = *reinterpret_cast<const uint4*>((const unsigned short*)A + aoff);
    uint4 pb = *reinterpret_cast<const uint4*>(Brow);
    for (int k0 = 0; k0 < K; k0 += 32) {
        uint4 av = pa, bv = pb;
        __syncthreads();
        *reinterpret_cast<uint4*>(&As[srow * 40 + schunk]) = av;
        *reinterpret_cast<uint4*>(&Bs[srow * 40 + schunk]) = bv;
        __syncthreads();
        if (k0 + 32 < K) {
            pa = *reinterpret_cast<const uint4*>((const unsigned short*)A + aoff + k0 + 32);
            pb = *reinterpret_cast<const uint4*>(Brow + k0 + 32);
        }
        bf16x8 af = *reinterpret_cast<const bf16x8*>(&As[arow * 40 + koff]);
        bf16x8 bf0 = *reinterpret_cast<const bf16x8*>(&Bs[(0 + nlo) * 40 + koff]);
        bf16x8 bf1 = *reinterpret_cast<const bf16x8*>(&Bs[(16 + nlo) * 40 + koff]);
        bf16x8 bf2 = *reinterpret_cast<const bf16x8*>(&Bs[(32 + nlo) * 40 + koff]);
        bf16x8 bf3 = *reinterpret_cast<const bf16x8*>(&Bs[(48 + nlo) * 40 + koff]);
        acc0 = __builtin_amdgcn_mfma_f32_16x16x32_bf16(af, bf0, acc0, 0, 0, 0);
        acc1 = __builtin_amdgcn_mfma_f32_16x16x32_bf16(af, bf1, acc1, 0, 0, 0);
        acc2 = __builtin_amdgcn_mfma_f32_16x16x32_bf16(af, bf2, acc2, 0, 0, 0);
        acc3 = __builtin_amdgcn_mfma_f32_16x16x32_bf16(af, bf3, acc3, 0, 0, 0);
    }
    int crow = msub + (lane >> 4) * 4;
    int ccol = lane & 15;
    floatx4 accs[4] = {acc0, acc1, acc2, acc3};
#pragma unroll
    for (int j = 0; j < 4; ++j) {
#pragma unroll
        for (int r = 0; r < 4; ++r) {
            C[(size_t)(m0 + crow + r) * N + (n0 + j * 16 + ccol)] = accs[j][r];
        }
    }
}

// ---------------- GCN aggregation layer 1 (256 cols, both graphs) ----------------

__global__ __launch_bounds__(256) void k_agg1(const float* __restrict__ xw1,
                                              const int* __restrict__ row_ptr,
                                              const int* __restrict__ col,
                                              const float* __restrict__ dinv,
                                              const int* __restrict__ perm,
                                              const float* __restrict__ b1,
                                              __hip_bfloat16* __restrict__ h_all, int n) {
    int lane = threadIdx.x & 63;
    int i = blockIdx.x * 4 + (threadIdx.x >> 6);
    float di = dinv[i];
    int pi = perm[i];
    float sw = di * di;
    int c4 = lane * 4;
    floatx4 acc = sw * *reinterpret_cast<const floatx4*>(xw1 + (size_t)i * H1 + c4);
    floatx4 accc = sw * *reinterpret_cast<const floatx4*>(xw1 + (size_t)pi * H1 + c4);
    int s = row_ptr[i], e = row_ptr[i + 1];
#pragma unroll 4
    for (int t = s; t < e; ++t) {
        int j = col[t];
        float wv = di * dinv[j];
        int pj = perm[j];
        acc += wv * *reinterpret_cast<const floatx4*>(xw1 + (size_t)j * H1 + c4);
        accc += wv * *reinterpret_cast<const floatx4*>(xw1 + (size_t)pj * H1 + c4);
    }
    floatx4 b4 = *reinterpret_cast<const floatx4*>(b1 + c4);
    ushort4 h0, h1;
    h0.x = f2b(fmaxf(acc[0] + b4[0], 0.f));
    h0.y = f2b(fmaxf(acc[1] + b4[1], 0.f));
    h0.z = f2b(fmaxf(acc[2] + b4[2], 0.f));
    h0.w = f2b(fmaxf(acc[3] + b4[3], 0.f));
    h1.x = f2b(fmaxf(accc[0] + b4[0], 0.f));
    h1.y = f2b(fmaxf(accc[1] + b4[1], 0.f));
    h1.z = f2b(fmaxf(accc[2] + b4[2], 0.f));
    h1.w = f2b(fmaxf(accc[3] + b4[3], 0.f));
    *reinterpret_cast<ushort4*>(h_all + (size_t)i * H1 + c4) = h0;
    *reinterpret_cast<ushort4*>(h_all + (size_t)(n + i) * H1 + c4) = h1;
}

// ---------------- GCN aggregation layer 2 (64 cols, both graphs, fp32) ----------------

__global__ __launch_bounds__(256) void k_agg2(const float* __restrict__ hw_all,
                                              const int* __restrict__ row_ptr,
                                              const int* __restrict__ col,
                                              const float* __restrict__ dinv,
                                              const float* __restrict__ b2,
                                              float* __restrict__ x1_all,
                                              float* __restrict__ out_x1, int n) {
    int lane = threadIdx.x & 63;
    int i = blockIdx.x * 4 + (threadIdx.x >> 6);
    float di = dinv[i];
    float sw = di * di;
    float acc = sw * hw_all[(size_t)i * OUTD + lane];
    float accc = sw * hw_all[(size_t)(n + i) * OUTD + lane];
    int s = row_ptr[i], e = row_ptr[i + 1];
#pragma unroll 4
    for (int t = s; t < e; ++t) {
        int j = col[t];
        float wv = di * dinv[j];
        acc += wv * hw_all[(size_t)j * OUTD + lane];
        accc += wv * hw_all[(size_t)(n + j) * OUTD + lane];
    }
    float b = b2[lane];
    float v = fmaxf(acc + b, 0.f);
    float vc = fmaxf(accc + b, 0.f);
    x1_all[(size_t)i * OUTD + lane] = v;
    x1_all[(size_t)(n + i) * OUTD + lane] = vc;
    out_x1[(size_t)i * OUTD + lane] = v;
}

// ---------------- readout + bilinear, fused; global_load_lds streaming scan ----------------

__global__ __launch_bounds__(256) void k_readout(const float* __restrict__ mask,
                                                 const float* __restrict__ x1_all,
                                                 const float* __restrict__ Wd,
                                                 const float* __restrict__ bd,
                                                 float* __restrict__ ret1,
                                                 float* __restrict__ ret1c, int n) {
    __shared__ __align__(16) float ring[4][4][512];  // [wave][slot][floats] = 32 KB
    __shared__ uint2 ents[4][256];                   // per-wave entry list = 8 KB
    int lane = threadIdx.x & 63;
    int w = threadIdx.x >> 6;
    int row = blockIdx.x * 4 + w;
    const float* mrow = mask + (size_t)row * n;

    auto issue = [&](int c) {
        int slot = c & 3;
        const float* g0 = mrow + c * 512 + lane * 4;
        __builtin_amdgcn_global_load_lds((GV*)g0, (LV*)&ring[w][slot][0], 16, 0, 0);
        __builtin_amdgcn_global_load_lds((GV*)(g0 + 256), (LV*)&ring[w][slot][256], 16, 0, 0);
    };
    issue(0);
    issue(1);
    issue(2);

    int base = 0;      // wave-uniform running entry count
    float rs = 0.f;    // per-lane partial row sum
    unsigned long long below = (lane == 63) ? ~0ull >> 1 : (1ull << lane) - 1;
    for (int k = 0; k < 16; ++k) {
        if (k < 13) {
            issue(k + 3);
            asm volatile("s_waitcnt vmcnt(6)" ::: "memory");
        } else if (k == 13) {
            asm volatile("s_waitcnt vmcnt(4)" ::: "memory");
        } else if (k == 14) {
            asm volatile("s_waitcnt vmcnt(2)" ::: "memory");
        } else {
            asm volatile("s_waitcnt vmcnt(0)" ::: "memory");
        }
        int slot = k & 3;
        floatx4 q0 = *reinterpret_cast<floatx4*>(&ring[w][slot][lane * 4]);
        floatx4 q1 = *reinterpret_cast<floatx4*>(&ring[w][slot][256 + lane * 4]);
        int cb = k * 512 + lane * 4;
#pragma unroll
        for (int u = 0; u < 4; ++u) {
            float v = q0[u];
            unsigned long long bal = __ballot(v != 0.f);
            if (v != 0.f) {
                int r = base + __popcll(bal & below);
                if (r < 256) ents[w][r] = make_uint2((unsigned)(cb + u), __float_as_uint(v));
                rs += v;
            }
            base += __popcll(bal);
        }
#pragma unroll
        for (int u = 0; u < 4; ++u) {
            float v = q1[u];
            unsigned long long bal = __ballot(v != 0.f);
            if (v != 0.f) {
                int r = base + __popcll(bal & below);
                if (r < 256) ents[w][r] = make_uint2((unsigned)(cb + 256 + u), __float_as_uint(v));
                rs += v;
            }
            base += __popcll(bal);
        }
    }
#pragma unroll
    for (int off = 32; off; off >>= 1) rs += __shfl_xor(rs, off);

    int cnt = min(base, 256);
    float acc = 0.f, accc = 0.f;
#pragma unroll 2
    for (int e = 0; e < cnt; ++e) {
        uint2 ent = ents[w][e];           // wave-uniform broadcast read
        float m = __uint_as_float(ent.y);
        int j = (int)ent.x;
        acc += m * x1_all[(size_t)j * OUTD + lane];
        accc += m * x1_all[(size_t)(n + j) * OUTD + lane];
    }
    float rst = fmaxf(rs, 1e-20f);
    float g = acc / rst;
    float gc = accc / rst;
    float s1 = g * g, s2 = gc * gc;
#pragma unroll
    for (int off = 32; off; off >>= 1) {
        s1 += __shfl_xor(s1, off);
        s2 += __shfl_xor(s2, off);
    }
    float gn = g / fmaxf(sqrtf(s1), 1e-12f);
    float gnc = gc / fmaxf(sqrtf(s2), 1e-12f);
    float gsig = 1.f / (1.f + __expf(-gn));
    float gcsig = 1.f / (1.f + __expf(-gnc));
    float tg = 0.f, tgc = 0.f;
    const float* wrow = Wd + lane * 64;
#pragma unroll 8
    for (int j = 0; j < 64; ++j) {
        float gj = __shfl(gsig, j);
        float gcj = __shfl(gcsig, j);
        float wv = wrow[j];
        tg += wv * gj;
        tgc += wv * gcj;
    }
    float x = x1_all[(size_t)row * OUTD + lane];
    float xc = x1_all[(size_t)(n + row) * OUTD + lane];
    float r0 = x * tg, r1 = xc * tg, r2 = xc * tgc, r3 = x * tgc;
#pragma unroll
    for (int off = 32; off; off >>= 1) {
        r0 += __shfl_down(r0, off);
        r1 += __shfl_down(r1, off);
        r2 += __shfl_down(r2, off);
        r3 += __shfl_down(r3, off);
    }
    if (lane == 0) {
        float b = bd[0];
        ret1[(size_t)row * 2 + 0] = r0 + b;
        ret1[(size_t)row * 2 + 1] = r1 + b;
        ret1c[(size_t)row * 2 + 0] = r2 + b;
        ret1c[(size_t)row * 2 + 1] = r3 + b;
    }
}

// ---------------- host ----------------

extern "C" void kernel_launch(void* const* d_in, const int* in_sizes, int n_in,
                              void* d_out, int out_size, void* d_ws, size_t ws_size,
                              hipStream_t stream) {
    const float* gene = (const float*)d_in[0];
    const float* mask = (const float*)d_in[1];
    const float* W1 = (const float*)d_in[2];
    const float* b1 = (const float*)d_in[3];
    const float* W2 = (const float*)d_in[4];
    const float* b2 = (const float*)d_in[5];
    const float* Wd = (const float*)d_in[6];
    const float* bd = (const float*)d_in[7];
    const unsigned* eidx_raw = (const unsigned*)d_in[8];
    const unsigned* perm_raw = (const unsigned*)d_in[9];
    const int n = NN;
    const int E = in_sizes[8] / 2;  // 131072 logical edge count

    // workspace carve-up (256B aligned); peak ~19.3 MB
    char* base = (char*)d_ws;
    char* p = base;
    auto alloc = [&](size_t bytes) -> char* {
        char* r = p;
        p += (bytes + 255) & ~(size_t)255;
        return r;
    };
    int* flags = (int*)alloc(256);
    unsigned long long* tbuf = (unsigned long long*)alloc(256);  // stamp buffer
    int* eidx32 = (int*)alloc((size_t)2 * E * 4);
    int* perm32 = (int*)alloc((size_t)n * 4);
    int* deg = (int*)alloc((size_t)n * 4);
    int* row_ptr = (int*)alloc((size_t)(n + 1) * 4);
    int* cursor = (int*)alloc((size_t)n * 4);
    float* dinv = (float*)alloc((size_t)n * 4);
    int* col = (int*)alloc((size_t)E * 4);
    __hip_bfloat16* W2t = (__hip_bfloat16*)alloc((size_t)H1 * OUTD * 2);
    __hip_bfloat16* W1t = (__hip_bfloat16*)alloc((size_t)INDP * H1 * 2);  // padded ld
    float* xw1 = (float*)alloc((size_t)n * H1 * 4);                        // 8 MB
    __hip_bfloat16* h_all = (__hip_bfloat16*)alloc((size_t)2 * n * H1 * 2); // 8 MB
    size_t need = (size_t)(p - base);
    // aliases into dead buffers:
    float* hw_all = xw1;                         // 2n*64 fp32 = 4 MB (xw1 dead after agg1)
    float* x1_all = xw1 + (size_t)2 * n * OUTD;  // next 4 MB (exactly fills xw1's 8 MB)

    float* out_x1 = (float*)d_out;
    float* out_ret1 = out_x1 + (size_t)n * OUTD;
    float* out_ret1c = out_ret1 + (size_t)n * 2;

    if (ws_size < need) {
        k_probe<<<1, 64, 0, stream>>>(1000.f + (float)(ws_size >> 20), out_x1);
        return;
    }

    // ---- DIAGNOSTIC pipeline (round-3 kernels + stamps + spins) ----
    k_stamp<<<1, 64, 0, stream>>>(tbuf, 0);

    // stage A: prolog
    k_pre<<<3076, 256, 0, stream>>>(eidx_raw, perm_raw, flags, deg, W1, W2, W1t, W2t);
    k_prep<<<(2 * E + n + 255) / 256, 256, 0, stream>>>(eidx_raw, perm_raw, flags,
                                                        eidx32, perm32, deg, E, n);
    const int* srcv = eidx32;
    const int* dstv = eidx32 + E;
    k_scan<<<1, 1024, 0, stream>>>(deg, row_ptr, cursor, dinv, n);
    k_scatter<<<(E + 255) / 256, 256, 0, stream>>>(srcv, dstv, cursor, col, E);
    k_stamp<<<1, 64, 0, stream>>>(tbuf, 1);

    // stage B: gemm1
    k_gemm1<<<dim3(H1 / 64, n / 64), 256, 0, stream>>>(gene, W1t, xw1);
    k_stamp<<<1, 64, 0, stream>>>(tbuf, 2);

    // stage C: agg1
    k_agg1<<<n / 4, 256, 0, stream>>>(xw1, row_ptr, col, dinv, perm32, b1, h_all, n);
    k_stamp<<<1, 64, 0, stream>>>(tbuf, 3);

    // stage D: gemm2 + agg2
    k_gemm2<<<dim3(2 * n / 64, OUTD / 64), 256, 0, stream>>>(h_all, W2t, hw_all, 2 * n, OUTD, H1);
    k_agg2<<<n / 4, 256, 0, stream>>>(hw_all, row_ptr, col, dinv, b2, x1_all, out_x1, n);
    k_stamp<<<1, 64, 0, stream>>>(tbuf, 4);

    // stage E: readout
    k_readout<<<n / 4, 256, 0, stream>>>(mask, x1_all, Wd, bd, out_ret1, out_ret1c, n);
    k_stamp<<<1, 64, 0, stream>>>(tbuf, 5);

    // spins: dur_us of spin i = C + 4*T(stage i), C ~ 180us; order: A,B,C,D,E
    k_spin<<<1, 64, 0, stream>>>(tbuf, 0);
    k_spin<<<1, 64, 0, stream>>>(tbuf, 1);
    k_spin<<<1, 64, 0, stream>>>(tbuf, 2);
    k_spin<<<1, 64, 0, stream>>>(tbuf, 3);
    k_spin<<<1, 64, 0, stream>>>(tbuf, 4);
}

// Round 5
// 576.360 us; speedup vs baseline: 4.8241x; 4.8241x over previous
//
#include <hip/hip_runtime.h>
#include <hip/hip_bf16.h>

// Problem constants (fixed by reference)
#define NN 8192
#define NMASK 8191
#define IND 3000
#define INDP 3008   // padded K for W1t rows: 3008*2B = 6016 bytes, 16B-aligned rows
#define H1 256
#define OUTD 64

typedef __bf16 bf16x8 __attribute__((ext_vector_type(8)));
typedef float floatx4 __attribute__((ext_vector_type(4)));

typedef const __attribute__((address_space(1))) void GV;
typedef __attribute__((address_space(3))) void LV;

__device__ __forceinline__ unsigned short f2b(float f) {
    __hip_bfloat16 h = __float2bfloat16(f);
    unsigned short u;
    __builtin_memcpy(&u, &h, 2);
    return u;
}

// bf16x4 -> fp32x4 (bf16 is truncated fp32: shift<<16)
__device__ __forceinline__ floatx4 b4f(const __hip_bfloat16* p) {
    ushort4 u = *reinterpret_cast<const ushort4*>(p);
    floatx4 r;
    r[0] = __uint_as_float((unsigned)u.x << 16);
    r[1] = __uint_as_float((unsigned)u.y << 16);
    r[2] = __uint_as_float((unsigned)u.z << 16);
    r[3] = __uint_as_float((unsigned)u.w << 16);
    return r;
}

// ---------------- ws-size probe ----------------

__global__ void k_probe(float code, float* out) {
    if (threadIdx.x == 0 && blockIdx.x == 0) out[0] = code;
}

// ---------------- fused pre-pass: detect widths, zero cnt, zero W1t pad, transposes ----------------
// block 0/1: detect index width; blocks 2..9: zero cnt; blocks 10..11: zero W1t pad
// rows [3000,3008); blocks 12..3075: W1/W2 fp32->bf16 transposes.

__global__ void k_pre(const unsigned* __restrict__ eraw, const unsigned* __restrict__ praw,
                      int* __restrict__ flags, int* __restrict__ cnt,
                      const float* __restrict__ W1, const float* __restrict__ W2,
                      __hip_bfloat16* __restrict__ W1t, __hip_bfloat16* __restrict__ W2t) {
    int b = blockIdx.x;
    int t = threadIdx.x;
    if (b < 2) {
        const unsigned* r = (b == 0) ? eraw : praw;
        __shared__ int c;
        if (t == 0) c = 0;
        __syncthreads();
        int z = 0;
        for (int k = t; k < 2048; k += 256)
            if (r[2 * k + 1] == 0u) z++;
        atomicAdd(&c, z);
        __syncthreads();
        if (t == 0) flags[b] = (c > 1024) ? 1 : 0;
    } else if (b < 10) {
#pragma unroll
        for (int u = 0; u < 4; ++u) cnt[(b - 2) * 1024 + u * 256 + t] = 0;
    } else if (b < 12) {
        int idx = (b - 10) * 256 + t;  // 0..511, each covers 4 pad elems
#pragma unroll
        for (int u = 0; u < 4; ++u) {
            int k = idx * 4 + u;       // 0..2047
            int c = k >> 3;
            int r = 3000 + (k & 7);
            W1t[(size_t)c * INDP + r] = __float2bfloat16(0.f);
        }
    } else {
        int idx = (b - 12) * 256 + t;
        if (idx < IND * H1) {
            int r = idx / H1, c = idx % H1;
            W1t[(size_t)c * INDP + r] = __float2bfloat16(W1[idx]);
        } else {
            int j = idx - IND * H1;
            if (j < H1 * OUTD) {
                int r = j / OUTD, c = j % OUTD;
                W2t[(size_t)c * H1 + r] = __float2bfloat16(W2[j]);
            }
        }
    }
}

// ---------------- edge bucketing + perm normalization, one pass ----------------
// Fixed 64-slot buckets per node replace the CSR scan+scatter pair entirely.
// Degrees are Poisson(16): P(deg > 64) ~ 1e-15 -> overflow guard only.

__global__ void k_prep(const unsigned* __restrict__ eraw, const unsigned* __restrict__ praw,
                       const int* __restrict__ flags, int* __restrict__ perm32,
                       int* __restrict__ cnt, int* __restrict__ adj, int E, int n) {
    int i = blockIdx.x * blockDim.x + threadIdx.x;
    if (i < E) {
        int f = flags[0];
        unsigned s = f ? eraw[2 * (size_t)i] : eraw[i];
        unsigned d = f ? eraw[2 * (size_t)(E + i)] : eraw[E + i];
        int si = (int)(s & (unsigned)NMASK);
        int di = (int)(d & (unsigned)NMASK);
        int p = atomicAdd(&cnt[di], 1);
        if (p < 64) adj[(di << 6) | p] = si;
    } else {
        int j = i - E;
        if (j < n) {
            unsigned v = flags[1] ? praw[2 * (size_t)j] : praw[j];
            perm32[j] = (int)(v & (unsigned)NMASK);
        }
    }
}

// ---------------- GEMM1: xw1(bf16)[8192][256] = gene(fp32) @ W1 ----------------
// BM=64 BN=64 BK=64, reg-staged 2-phase prefetch. bf16 C halves agg1's gather bytes.

__global__ __launch_bounds__(256) void k_gemm1(const float* __restrict__ A,
                                               const __hip_bfloat16* __restrict__ Bt,
                                               unsigned short* __restrict__ C) {
    __shared__ __align__(16) unsigned short As[64 * 72];
    __shared__ __align__(16) unsigned short Bs[64 * 72];
    int t = threadIdx.x;
    int n0 = blockIdx.x * 64;
    int m0 = blockIdx.y * 64;
    int lane = t & 63;
    int w = t >> 6;
    int srow = t >> 2;
    int schunk = (t & 3) * 16;
    const float* Arow = A + (size_t)(m0 + srow) * IND + schunk;
    const unsigned short* Brow = (const unsigned short*)Bt + (size_t)(n0 + srow) * INDP + schunk;

    floatx4 acc0 = {0.f, 0.f, 0.f, 0.f}, acc1 = acc0, acc2 = acc0, acc3 = acc0;
    int msub = w * 16;
    int arow = msub + (lane & 15);
    int koff = (lane >> 4) * 8;
    int nlo = lane & 15;

    float4 pa0, pa1, pa2, pa3;
    uint4 pb0, pb1;
    auto load_tile = [&](int k0) {
        float4 z4 = make_float4(0.f, 0.f, 0.f, 0.f);
        uint4 zu = make_uint4(0u, 0u, 0u, 0u);
        pa0 = z4; pa1 = z4; pa2 = z4; pa3 = z4; pb0 = zu; pb1 = zu;
        int kk = k0 + schunk;
        if (kk < IND) {
            const float* ap = Arow + k0;
            pa0 = *reinterpret_cast<const float4*>(ap);
            pa1 = *reinterpret_cast<const float4*>(ap + 4);
            pb0 = *reinterpret_cast<const uint4*>(Brow + k0);
        }
        if (kk + 8 < IND) {
            const float* ap = Arow + k0 + 8;
            pa2 = *reinterpret_cast<const float4*>(ap);
            pa3 = *reinterpret_cast<const float4*>(ap + 4);
            pb1 = *reinterpret_cast<const uint4*>(Brow + k0 + 8);
        }
    };
    load_tile(0);
    for (int k0 = 0; k0 < IND; k0 += 64) {
        uint4 av0, av1, bv0 = pb0, bv1 = pb1;
        {
            unsigned short t8[8] = {f2b(pa0.x), f2b(pa0.y), f2b(pa0.z), f2b(pa0.w),
                                    f2b(pa1.x), f2b(pa1.y), f2b(pa1.z), f2b(pa1.w)};
            __builtin_memcpy(&av0, t8, 16);
        }
        {
            unsigned short t8[8] = {f2b(pa2.x), f2b(pa2.y), f2b(pa2.z), f2b(pa2.w),
                                    f2b(pa3.x), f2b(pa3.y), f2b(pa3.z), f2b(pa3.w)};
            __builtin_memcpy(&av1, t8, 16);
        }
        __syncthreads();
        *reinterpret_cast<uint4*>(&As[srow * 72 + schunk]) = av0;
        *reinterpret_cast<uint4*>(&As[srow * 72 + schunk + 8]) = av1;
        *reinterpret_cast<uint4*>(&Bs[srow * 72 + schunk]) = bv0;
        *reinterpret_cast<uint4*>(&Bs[srow * 72 + schunk + 8]) = bv1;
        __syncthreads();
        if (k0 + 64 < IND) load_tile(k0 + 64);
#pragma unroll
        for (int ks = 0; ks < 64; ks += 32) {
            bf16x8 af = *reinterpret_cast<const bf16x8*>(&As[arow * 72 + ks + koff]);
            bf16x8 b0 = *reinterpret_cast<const bf16x8*>(&Bs[(0 + nlo) * 72 + ks + koff]);
            bf16x8 b1 = *reinterpret_cast<const bf16x8*>(&Bs[(16 + nlo) * 72 + ks + koff]);
            bf16x8 b2 = *reinterpret_cast<const bf16x8*>(&Bs[(32 + nlo) * 72 + ks + koff]);
            bf16x8 b3 = *reinterpret_cast<const bf16x8*>(&Bs[(48 + nlo) * 72 + ks + koff]);
            acc0 = __builtin_amdgcn_mfma_f32_16x16x32_bf16(af, b0, acc0, 0, 0, 0);
            acc1 = __builtin_amdgcn_mfma_f32_16x16x32_bf16(af, b1, acc1, 0, 0, 0);
            acc2 = __builtin_amdgcn_mfma_f32_16x16x32_bf16(af, b2, acc2, 0, 0, 0);
            acc3 = __builtin_amdgcn_mfma_f32_16x16x32_bf16(af, b3, acc3, 0, 0, 0);
        }
    }
    // C/D layout: col = lane&15, row = (lane>>4)*4 + r   [verified m89/m91]
    int crow = msub + (lane >> 4) * 4;
    int ccol = lane & 15;
    floatx4 accs[4] = {acc0, acc1, acc2, acc3};
#pragma unroll
    for (int j = 0; j < 4; ++j) {
#pragma unroll
        for (int r = 0; r < 4; ++r) {
            C[(size_t)(m0 + crow + r) * H1 + (n0 + j * 16 + ccol)] = f2b(accs[j][r]);
        }
    }
}

// ---------------- GEMM2: hw_all = h_all(bf16) @ W2, BM=64 BN=64 BK=32, reg-prefetch ----------------

__global__ __launch_bounds__(256) void k_gemm2(const __hip_bfloat16* __restrict__ A,
                                               const __hip_bfloat16* __restrict__ Bt,
                                               float* __restrict__ C,
                                               int M, int N, int K) {
    __shared__ __align__(16) unsigned short As[64 * 40];
    __shared__ __align__(16) unsigned short Bs[64 * 40];
    int t = threadIdx.x;
    int m0 = blockIdx.x * 64;
    int n0 = blockIdx.y * 64;
    int lane = t & 63;
    int w = t >> 6;
    int srow = t >> 2;
    int schunk = (t & 3) * 8;
    size_t aoff = (size_t)(m0 + srow) * K + schunk;
    const unsigned short* Brow = (const unsigned short*)Bt + (size_t)(n0 + srow) * K + schunk;

    floatx4 acc0 = {0.f, 0.f, 0.f, 0.f}, acc1 = acc0, acc2 = acc0, acc3 = acc0;
    int msub = w * 16;
    int arow = msub + (lane & 15);
    int koff = (lane >> 4) * 8;
    int nlo = lane & 15;

    uint4 pa = *reinterpret_cast<const uint4*>((const unsigned short*)A + aoff);
    uint4 pb = *reinterpret_cast<const uint4*>(Brow);
    for (int k0 = 0; k0 < K; k0 += 32) {
        uint4 av = pa, bv = pb;
        __syncthreads();
        *reinterpret_cast<uint4*>(&As[srow * 40 + schunk]) = av;
        *reinterpret_cast<uint4*>(&Bs[srow * 40 + schunk]) = bv;
        __syncthreads();
        if (k0 + 32 < K) {
            pa = *reinterpret_cast<const uint4*>((const unsigned short*)A + aoff + k0 + 32);
            pb = *reinterpret_cast<const uint4*>(Brow + k0 + 32);
        }
        bf16x8 af = *reinterpret_cast<const bf16x8*>(&As[arow * 40 + koff]);
        bf16x8 bf0 = *reinterpret_cast<const bf16x8*>(&Bs[(0 + nlo) * 40 + koff]);
        bf16x8 bf1 = *reinterpret_cast<const bf16x8*>(&Bs[(16 + nlo) * 40 + koff]);
        bf16x8 bf2 = *reinterpret_cast<const bf16x8*>(&Bs[(32 + nlo) * 40 + koff]);
        bf16x8 bf3 = *reinterpret_cast<const bf16x8*>(&Bs[(48 + nlo) * 40 + koff]);
        acc0 = __builtin_amdgcn_mfma_f32_16x16x32_bf16(af, bf0, acc0, 0, 0, 0);
        acc1 = __builtin_amdgcn_mfma_f32_16x16x32_bf16(af, bf1, acc1, 0, 0, 0);
        acc2 = __builtin_amdgcn_mfma_f32_16x16x32_bf16(af, bf2, acc2, 0, 0, 0);
        acc3 = __builtin_amdgcn_mfma_f32_16x16x32_bf16(af, bf3, acc3, 0, 0, 0);
    }
    int crow = msub + (lane >> 4) * 4;
    int ccol = lane & 15;
    floatx4 accs[4] = {acc0, acc1, acc2, acc3};
#pragma unroll
    for (int j = 0; j < 4; ++j) {
#pragma unroll
        for (int r = 0; r < 4; ++r) {
            C[(size_t)(m0 + crow + r) * N + (n0 + j * 16 + ccol)] = accs[j][r];
        }
    }
}

// ---------------- GCN aggregation layer 1 (bf16 xw1, 256 cols, both graphs) ----------------
// one wave per row; lane holds 4 cols (ushort4 = 8B/lane, 512B row per wave-load);
// dinv computed inline from cnt (no dinv array).

__global__ __launch_bounds__(256) void k_agg1(const __hip_bfloat16* __restrict__ xw1,
                                              const int* __restrict__ cnt,
                                              const int* __restrict__ adj,
                                              const int* __restrict__ perm,
                                              const float* __restrict__ b1,
                                              __hip_bfloat16* __restrict__ h_all, int n) {
    int lane = threadIdx.x & 63;
    int i = blockIdx.x * 4 + (threadIdx.x >> 6);
    int ci = cnt[i];
    float di = rsqrtf((float)(1 + ci));
    int pi = perm[i];
    float sw = di * di;
    int c4 = lane * 4;
    floatx4 acc = sw * b4f(xw1 + (size_t)i * H1 + c4);
    floatx4 accc = sw * b4f(xw1 + (size_t)pi * H1 + c4);
    int e = min(ci, 64);
    const int* arow = adj + ((size_t)i << 6);
#pragma unroll 4
    for (int t = 0; t < e; ++t) {
        int j = arow[t];
        float wv = di * rsqrtf((float)(1 + cnt[j]));
        int pj = perm[j];
        acc += wv * b4f(xw1 + (size_t)j * H1 + c4);
        accc += wv * b4f(xw1 + (size_t)pj * H1 + c4);
    }
    floatx4 b4 = *reinterpret_cast<const floatx4*>(b1 + c4);
    ushort4 h0, h1;
    h0.x = f2b(fmaxf(acc[0] + b4[0], 0.f));
    h0.y = f2b(fmaxf(acc[1] + b4[1], 0.f));
    h0.z = f2b(fmaxf(acc[2] + b4[2], 0.f));
    h0.w = f2b(fmaxf(acc[3] + b4[3], 0.f));
    h1.x = f2b(fmaxf(accc[0] + b4[0], 0.f));
    h1.y = f2b(fmaxf(accc[1] + b4[1], 0.f));
    h1.z = f2b(fmaxf(accc[2] + b4[2], 0.f));
    h1.w = f2b(fmaxf(accc[3] + b4[3], 0.f));
    *reinterpret_cast<ushort4*>(h_all + (size_t)i * H1 + c4) = h0;
    *reinterpret_cast<ushort4*>(h_all + (size_t)(n + i) * H1 + c4) = h1;
}

// ---------------- GCN aggregation layer 2 (64 cols, both graphs, fp32) ----------------

__global__ __launch_bounds__(256) void k_agg2(const float* __restrict__ hw_all,
                                              const int* __restrict__ cnt,
                                              const int* __restrict__ adj,
                                              const float* __restrict__ b2,
                                              float* __restrict__ x1_all,
                                              float* __restrict__ out_x1, int n) {
    int lane = threadIdx.x & 63;
    int i = blockIdx.x * 4 + (threadIdx.x >> 6);
    int ci = cnt[i];
    float di = rsqrtf((float)(1 + ci));
    float sw = di * di;
    float acc = sw * hw_all[(size_t)i * OUTD + lane];
    float accc = sw * hw_all[(size_t)(n + i) * OUTD + lane];
    int e = min(ci, 64);
    const int* arow = adj + ((size_t)i << 6);
#pragma unroll 4
    for (int t = 0; t < e; ++t) {
        int j = arow[t];
        float wv = di * rsqrtf((float)(1 + cnt[j]));
        acc += wv * hw_all[(size_t)j * OUTD + lane];
        accc += wv * hw_all[(size_t)(n + j) * OUTD + lane];
    }
    float b = b2[lane];
    float v = fmaxf(acc + b, 0.f);
    float vc = fmaxf(accc + b, 0.f);
    x1_all[(size_t)i * OUTD + lane] = v;
    x1_all[(size_t)(n + i) * OUTD + lane] = vc;
    out_x1[(size_t)i * OUTD + lane] = v;
}

// ---------------- readout + bilinear, fused; global_load_lds streaming scan ----------------

__global__ __launch_bounds__(256) void k_readout(const float* __restrict__ mask,
                                                 const float* __restrict__ x1_all,
                                                 const float* __restrict__ Wd,
                                                 const float* __restrict__ bd,
                                                 float* __restrict__ ret1,
                                                 float* __restrict__ ret1c, int n) {
    __shared__ __align__(16) float ring[4][4][512];  // [wave][slot][floats] = 32 KB
    __shared__ uint2 ents[4][256];                   // per-wave entry list = 8 KB
    int lane = threadIdx.x & 63;
    int w = threadIdx.x >> 6;
    int row = blockIdx.x * 4 + w;
    const float* mrow = mask + (size_t)row * n;

    auto issue = [&](int c) {
        int slot = c & 3;
        const float* g0 = mrow + c * 512 + lane * 4;
        __builtin_amdgcn_global_load_lds((GV*)g0, (LV*)&ring[w][slot][0], 16, 0, 0);
        __builtin_amdgcn_global_load_lds((GV*)(g0 + 256), (LV*)&ring[w][slot][256], 16, 0, 0);
    };
    issue(0);
    issue(1);
    issue(2);

    int base = 0;      // wave-uniform running entry count
    float rs = 0.f;    // per-lane partial row sum
    unsigned long long below = (lane == 63) ? ~0ull >> 1 : (1ull << lane) - 1;
    for (int k = 0; k < 16; ++k) {
        if (k < 13) {
            issue(k + 3);
            asm volatile("s_waitcnt vmcnt(6)" ::: "memory");
        } else if (k == 13) {
            asm volatile("s_waitcnt vmcnt(4)" ::: "memory");
        } else if (k == 14) {
            asm volatile("s_waitcnt vmcnt(2)" ::: "memory");
        } else {
            asm volatile("s_waitcnt vmcnt(0)" ::: "memory");
        }
        int slot = k & 3;
        floatx4 q0 = *reinterpret_cast<floatx4*>(&ring[w][slot][lane * 4]);
        floatx4 q1 = *reinterpret_cast<floatx4*>(&ring[w][slot][256 + lane * 4]);
        int cb = k * 512 + lane * 4;
#pragma unroll
        for (int u = 0; u < 4; ++u) {
            float v = q0[u];
            unsigned long long bal = __ballot(v != 0.f);
            if (v != 0.f) {
                int r = base + __popcll(bal & below);
                if (r < 256) ents[w][r] = make_uint2((unsigned)(cb + u), __float_as_uint(v));
                rs += v;
            }
            base += __popcll(bal);
        }
#pragma unroll
        for (int u = 0; u < 4; ++u) {
            float v = q1[u];
            unsigned long long bal = __ballot(v != 0.f);
            if (v != 0.f) {
                int r = base + __popcll(bal & below);
                if (r < 256) ents[w][r] = make_uint2((unsigned)(cb + 256 + u), __float_as_uint(v));
                rs += v;
            }
            base += __popcll(bal);
        }
    }
#pragma unroll
    for (int off = 32; off; off >>= 1) rs += __shfl_xor(rs, off);

    int cnt = min(base, 256);
    float acc = 0.f, accc = 0.f;
#pragma unroll 2
    for (int e = 0; e < cnt; ++e) {
        uint2 ent = ents[w][e];           // wave-uniform broadcast read
        float m = __uint_as_float(ent.y);
        int j = (int)ent.x;
        acc += m * x1_all[(size_t)j * OUTD + lane];
        accc += m * x1_all[(size_t)(n + j) * OUTD + lane];
    }
    float rst = fmaxf(rs, 1e-20f);
    float g = acc / rst;
    float gc = accc / rst;
    float s1 = g * g, s2 = gc * gc;
#pragma unroll
    for (int off = 32; off; off >>= 1) {
        s1 += __shfl_xor(s1, off);
        s2 += __shfl_xor(s2, off);
    }
    float gn = g / fmaxf(sqrtf(s1), 1e-12f);
    float gnc = gc / fmaxf(sqrtf(s2), 1e-12f);
    float gsig = 1.f / (1.f + __expf(-gn));
    float gcsig = 1.f / (1.f + __expf(-gnc));
    float tg = 0.f, tgc = 0.f;
    const float* wrow = Wd + lane * 64;
#pragma unroll 8
    for (int j = 0; j < 64; ++j) {
        float gj = __shfl(gsig, j);
        float gcj = __shfl(gcsig, j);
        float wv = wrow[j];
        tg += wv * gj;
        tgc += wv * gcj;
    }
    float x = x1_all[(size_t)row * OUTD + lane];
    float xc = x1_all[(size_t)(n + row) * OUTD + lane];
    float r0 = x * tg, r1 = xc * tg, r2 = xc * tgc, r3 = x * tgc;
#pragma unroll
    for (int off = 32; off; off >>= 1) {
        r0 += __shfl_down(r0, off);
        r1 += __shfl_down(r1, off);
        r2 += __shfl_down(r2, off);
        r3 += __shfl_down(r3, off);
    }
    if (lane == 0) {
        float b = bd[0];
        ret1[(size_t)row * 2 + 0] = r0 + b;
        ret1[(size_t)row * 2 + 1] = r1 + b;
        ret1c[(size_t)row * 2 + 0] = r2 + b;
        ret1c[(size_t)row * 2 + 1] = r3 + b;
    }
}

// ---------------- host ----------------

extern "C" void kernel_launch(void* const* d_in, const int* in_sizes, int n_in,
                              void* d_out, int out_size, void* d_ws, size_t ws_size,
                              hipStream_t stream) {
    const float* gene = (const float*)d_in[0];
    const float* mask = (const float*)d_in[1];
    const float* W1 = (const float*)d_in[2];
    const float* b1 = (const float*)d_in[3];
    const float* W2 = (const float*)d_in[4];
    const float* b2 = (const float*)d_in[5];
    const float* Wd = (const float*)d_in[6];
    const float* bd = (const float*)d_in[7];
    const unsigned* eidx_raw = (const unsigned*)d_in[8];
    const unsigned* perm_raw = (const unsigned*)d_in[9];
    const int n = NN;
    const int E = in_sizes[8] / 2;  // 131072 logical edge count

    // workspace carve-up (256B aligned); peak ~15.7 MB
    char* base = (char*)d_ws;
    char* p = base;
    auto alloc = [&](size_t bytes) -> char* {
        char* r = p;
        p += (bytes + 255) & ~(size_t)255;
        return r;
    };
    int* flags = (int*)alloc(256);
    int* cnt = (int*)alloc((size_t)n * 4);
    int* adj = (int*)alloc((size_t)n * 64 * 4);                            // 2 MB
    int* perm32 = (int*)alloc((size_t)n * 4);
    __hip_bfloat16* W2t = (__hip_bfloat16*)alloc((size_t)H1 * OUTD * 2);
    __hip_bfloat16* W1t = (__hip_bfloat16*)alloc((size_t)INDP * H1 * 2);   // padded ld
    __hip_bfloat16* xw1b = (__hip_bfloat16*)alloc((size_t)n * H1 * 2);     // 4 MB
    __hip_bfloat16* h_all = (__hip_bfloat16*)alloc((size_t)2 * n * H1 * 2);// 8 MB
    size_t need = (size_t)(p - base);
    // aliases into dead buffers:
    float* hw_all = (float*)xw1b;   // 2n*64 fp32 = 4 MB (xw1b dead after agg1)
    float* x1_all = (float*)h_all;  // 2n*64 fp32 = 4 MB (h_all dead after gemm2)

    float* out_x1 = (float*)d_out;
    float* out_ret1 = out_x1 + (size_t)n * OUTD;
    float* out_ret1c = out_ret1 + (size_t)n * 2;

    if (ws_size < need) {
        k_probe<<<1, 64, 0, stream>>>(1000.f + (float)(ws_size >> 20), out_x1);
        return;
    }

    // 0. fused pre-pass: detect widths, zero cnt, zero W1t pad, transposes
    k_pre<<<3076, 256, 0, stream>>>(eidx_raw, perm_raw, flags, cnt, W1, W2, W1t, W2t);

    // 1. edge bucketing (64-slot buckets; replaces degree+scan+scatter) + perm norm
    k_prep<<<(E + n) / 256, 256, 0, stream>>>(eidx_raw, perm_raw, flags,
                                              perm32, cnt, adj, E, n);

    // 2. GEMM1: xw1(bf16) = gene @ W1
    k_gemm1<<<dim3(H1 / 64, n / 64), 256, 0, stream>>>(gene, W1t, (unsigned short*)xw1b);

    // 3. conv1 aggregation (both graphs) -> h_all bf16 [2n x 256]
    k_agg1<<<n / 4, 256, 0, stream>>>(xw1b, cnt, adj, perm32, b1, h_all, n);

    // 4. GEMM2: hw_all = h_all(bf16) @ W2  (writes into dead xw1b region)
    k_gemm2<<<dim3(2 * n / 64, OUTD / 64), 256, 0, stream>>>(h_all, W2t, hw_all, 2 * n, OUTD, H1);

    // 5. conv2 aggregation -> x1_all fp32 [2n x 64]; x1 also to d_out
    k_agg2<<<n / 4, 256, 0, stream>>>(hw_all, cnt, adj, b2, x1_all, out_x1, n);

    // 6. readout + bilinear fused (global_load_lds streaming scan) -> ret1, ret1_c
    k_readout<<<n / 4, 256, 0, stream>>>(mask, x1_all, Wd, bd, out_ret1, out_ret1c, n);
}

// Round 6
// 545.438 us; speedup vs baseline: 5.0976x; 1.0567x over previous
//
#include <hip/hip_runtime.h>
#include <hip/hip_bf16.h>

// Problem constants (fixed by reference)
#define NN 8192
#define NMASK 8191
#define IND 3000
#define INDP 3008   // padded K for W1t rows: 3008*2B = 6016 bytes, 16B-aligned rows
#define H1 256
#define OUTD 64

// mega-kernel block families
#define GB 512      // gemm1 blocks (4 n-panels x 128 m-panels)
#define SB 2048     // mask-scan blocks (4 rows each)
#define PB 544      // prep blocks ((131072 + 8192)/256)

typedef __bf16 bf16x8 __attribute__((ext_vector_type(8)));
typedef float floatx4 __attribute__((ext_vector_type(4)));

typedef const __attribute__((address_space(1))) void GV;
typedef __attribute__((address_space(3))) void LV;

__device__ __forceinline__ unsigned short f2b(float f) {
    __hip_bfloat16 h = __float2bfloat16(f);
    unsigned short u;
    __builtin_memcpy(&u, &h, 2);
    return u;
}

// bf16x4 -> fp32x4 (bf16 is truncated fp32: shift<<16)
__device__ __forceinline__ floatx4 b4f(const __hip_bfloat16* p) {
    ushort4 u = *reinterpret_cast<const ushort4*>(p);
    floatx4 r;
    r[0] = __uint_as_float((unsigned)u.x << 16);
    r[1] = __uint_as_float((unsigned)u.y << 16);
    r[2] = __uint_as_float((unsigned)u.z << 16);
    r[3] = __uint_as_float((unsigned)u.w << 16);
    return r;
}

// ---------------- ws-size probe ----------------

__global__ void k_probe(float code, float* out) {
    if (threadIdx.x == 0 && blockIdx.x == 0) out[0] = code;
}

// ---------------- pre-pass: detect widths, zero W1t pad, weight transposes ----------------
// (cnt zeroing moved to hipMemsetAsync)

__global__ void k_pre(const unsigned* __restrict__ eraw, const unsigned* __restrict__ praw,
                      int* __restrict__ flags,
                      const float* __restrict__ W1, const float* __restrict__ W2,
                      __hip_bfloat16* __restrict__ W1t, __hip_bfloat16* __restrict__ W2t) {
    int b = blockIdx.x;
    int t = threadIdx.x;
    if (b < 2) {
        const unsigned* r = (b == 0) ? eraw : praw;
        __shared__ int c;
        if (t == 0) c = 0;
        __syncthreads();
        int z = 0;
        for (int k = t; k < 2048; k += 256)
            if (r[2 * k + 1] == 0u) z++;
        atomicAdd(&c, z);
        __syncthreads();
        if (t == 0) flags[b] = (c > 1024) ? 1 : 0;
    } else if (b < 4) {
        int idx = (b - 2) * 256 + t;  // 0..511, each covers 4 pad elems
#pragma unroll
        for (int u = 0; u < 4; ++u) {
            int k = idx * 4 + u;      // 0..2047 = 8 pad rows x 256 cols
            int c = k >> 3;
            int r = 3000 + (k & 7);
            W1t[(size_t)c * INDP + r] = __float2bfloat16(0.f);
        }
    } else {
        int idx = (b - 4) * 256 + t;
        if (idx < IND * H1) {
            int r = idx / H1, c = idx % H1;
            W1t[(size_t)c * INDP + r] = __float2bfloat16(W1[idx]);
        } else {
            int j = idx - IND * H1;
            if (j < H1 * OUTD) {
                int r = j / OUTD, c = j % OUTD;
                W2t[(size_t)c * H1 + r] = __float2bfloat16(W2[j]);
            }
        }
    }
}

// ---------------- mega-kernel bodies ----------------

// GEMM1: xw1(bf16)[8192][256] = gene(fp32) @ W1. BM=64 BN=64 BK=64, reg-prefetch.
__device__ __forceinline__ void gemm1_body(char* smem, int blk,
                                           const float* __restrict__ A,
                                           const __hip_bfloat16* __restrict__ Bt,
                                           unsigned short* __restrict__ C) {
    unsigned short* As = (unsigned short*)smem;           // 64*72*2 = 9216 B
    unsigned short* Bs = As + 64 * 72;                    // +9216 B (18.4 KB total)
    int t = threadIdx.x;
    int n0 = (blk & 3) * 64;   // 4 consecutive blocks share one A panel
    int m0 = (blk >> 2) * 64;
    int lane = t & 63;
    int w = t >> 6;
    int srow = t >> 2;
    int schunk = (t & 3) * 16;
    const float* Arow = A + (size_t)(m0 + srow) * IND + schunk;
    const unsigned short* Brow = (const unsigned short*)Bt + (size_t)(n0 + srow) * INDP + schunk;

    floatx4 acc0 = {0.f, 0.f, 0.f, 0.f}, acc1 = acc0, acc2 = acc0, acc3 = acc0;
    int msub = w * 16;
    int arow = msub + (lane & 15);
    int koff = (lane >> 4) * 8;
    int nlo = lane & 15;

    float4 pa0, pa1, pa2, pa3;
    uint4 pb0, pb1;
    auto load_tile = [&](int k0) {
        float4 z4 = make_float4(0.f, 0.f, 0.f, 0.f);
        uint4 zu = make_uint4(0u, 0u, 0u, 0u);
        pa0 = z4; pa1 = z4; pa2 = z4; pa3 = z4; pb0 = zu; pb1 = zu;
        int kk = k0 + schunk;
        if (kk < IND) {
            const float* ap = Arow + k0;
            pa0 = *reinterpret_cast<const float4*>(ap);
            pa1 = *reinterpret_cast<const float4*>(ap + 4);
            pb0 = *reinterpret_cast<const uint4*>(Brow + k0);
        }
        if (kk + 8 < IND) {
            const float* ap = Arow + k0 + 8;
            pa2 = *reinterpret_cast<const float4*>(ap);
            pa3 = *reinterpret_cast<const float4*>(ap + 4);
            pb1 = *reinterpret_cast<const uint4*>(Brow + k0 + 8);
        }
    };
    load_tile(0);
    for (int k0 = 0; k0 < IND; k0 += 64) {
        uint4 av0, av1, bv0 = pb0, bv1 = pb1;
        {
            unsigned short t8[8] = {f2b(pa0.x), f2b(pa0.y), f2b(pa0.z), f2b(pa0.w),
                                    f2b(pa1.x), f2b(pa1.y), f2b(pa1.z), f2b(pa1.w)};
            __builtin_memcpy(&av0, t8, 16);
        }
        {
            unsigned short t8[8] = {f2b(pa2.x), f2b(pa2.y), f2b(pa2.z), f2b(pa2.w),
                                    f2b(pa3.x), f2b(pa3.y), f2b(pa3.z), f2b(pa3.w)};
            __builtin_memcpy(&av1, t8, 16);
        }
        __syncthreads();
        *reinterpret_cast<uint4*>(&As[srow * 72 + schunk]) = av0;
        *reinterpret_cast<uint4*>(&As[srow * 72 + schunk + 8]) = av1;
        *reinterpret_cast<uint4*>(&Bs[srow * 72 + schunk]) = bv0;
        *reinterpret_cast<uint4*>(&Bs[srow * 72 + schunk + 8]) = bv1;
        __syncthreads();
        if (k0 + 64 < IND) load_tile(k0 + 64);
#pragma unroll
        for (int ks = 0; ks < 64; ks += 32) {
            bf16x8 af = *reinterpret_cast<const bf16x8*>(&As[arow * 72 + ks + koff]);
            bf16x8 b0 = *reinterpret_cast<const bf16x8*>(&Bs[(0 + nlo) * 72 + ks + koff]);
            bf16x8 b1 = *reinterpret_cast<const bf16x8*>(&Bs[(16 + nlo) * 72 + ks + koff]);
            bf16x8 b2 = *reinterpret_cast<const bf16x8*>(&Bs[(32 + nlo) * 72 + ks + koff]);
            bf16x8 b3 = *reinterpret_cast<const bf16x8*>(&Bs[(48 + nlo) * 72 + ks + koff]);
            acc0 = __builtin_amdgcn_mfma_f32_16x16x32_bf16(af, b0, acc0, 0, 0, 0);
            acc1 = __builtin_amdgcn_mfma_f32_16x16x32_bf16(af, b1, acc1, 0, 0, 0);
            acc2 = __builtin_amdgcn_mfma_f32_16x16x32_bf16(af, b2, acc2, 0, 0, 0);
            acc3 = __builtin_amdgcn_mfma_f32_16x16x32_bf16(af, b3, acc3, 0, 0, 0);
        }
    }
    // C/D layout: col = lane&15, row = (lane>>4)*4 + r   [verified m89/m91]
    int crow = msub + (lane >> 4) * 4;
    int ccol = lane & 15;
    floatx4 accs[4] = {acc0, acc1, acc2, acc3};
#pragma unroll
    for (int j = 0; j < 4; ++j) {
#pragma unroll
        for (int r = 0; r < 4; ++r) {
            C[(size_t)(m0 + crow + r) * H1 + (n0 + j * 16 + ccol)] = f2b(accs[j][r]);
        }
    }
}

// mask scan: compact nonzeros of 4 rows into global 64-slot buckets + rowsums.
// 4-slot LDS ring per wave via global_load_lds, counted vmcnt (never 0 mid-loop).
// Entry stores (vmem) interleave with the counted load stream: vmcnt is FIFO per
// wave, so vmcnt(6) still guarantees chunk-k's 2 loads have landed (conservative).
__device__ __forceinline__ void scan_body(char* smem, int blk,
                                          const float* __restrict__ mask,
                                          uint2* __restrict__ ents_g,
                                          float* __restrict__ rsum,
                                          int* __restrict__ rcnt, int n) {
    float (*ring)[4][512] = reinterpret_cast<float (*)[4][512]>(smem);  // 32 KB
    int lane = threadIdx.x & 63;
    int w = threadIdx.x >> 6;
    int row = blk * 4 + w;
    const float* mrow = mask + (size_t)row * n;
    uint2* erow = ents_g + ((size_t)row << 6);

    auto issue = [&](int c) {
        int slot = c & 3;
        const float* g0 = mrow + c * 512 + lane * 4;
        __builtin_amdgcn_global_load_lds((GV*)g0, (LV*)&ring[w][slot][0], 16, 0, 0);
        __builtin_amdgcn_global_load_lds((GV*)(g0 + 256), (LV*)&ring[w][slot][256], 16, 0, 0);
    };
    issue(0);
    issue(1);
    issue(2);

    int base = 0;      // wave-uniform running entry count
    float rs = 0.f;    // per-lane partial row sum
    unsigned long long below = (lane == 63) ? ~0ull >> 1 : (1ull << lane) - 1;
    for (int k = 0; k < 16; ++k) {
        if (k < 13) {
            issue(k + 3);
            asm volatile("s_waitcnt vmcnt(6)" ::: "memory");
        } else if (k == 13) {
            asm volatile("s_waitcnt vmcnt(4)" ::: "memory");
        } else if (k == 14) {
            asm volatile("s_waitcnt vmcnt(2)" ::: "memory");
        } else {
            asm volatile("s_waitcnt vmcnt(0)" ::: "memory");
        }
        int slot = k & 3;
        floatx4 q0 = *reinterpret_cast<floatx4*>(&ring[w][slot][lane * 4]);
        floatx4 q1 = *reinterpret_cast<floatx4*>(&ring[w][slot][256 + lane * 4]);
        int cb = k * 512 + lane * 4;
#pragma unroll
        for (int u = 0; u < 4; ++u) {
            float v = q0[u];
            unsigned long long bal = __ballot(v != 0.f);
            if (v != 0.f) {
                int r = base + __popcll(bal & below);
                if (r < 64) erow[r] = make_uint2((unsigned)(cb + u), __float_as_uint(v));
                rs += v;
            }
            base += __popcll(bal);
        }
#pragma unroll
        for (int u = 0; u < 4; ++u) {
            float v = q1[u];
            unsigned long long bal = __ballot(v != 0.f);
            if (v != 0.f) {
                int r = base + __popcll(bal & below);
                if (r < 64) erow[r] = make_uint2((unsigned)(cb + 256 + u), __float_as_uint(v));
                rs += v;
            }
            base += __popcll(bal);
        }
    }
#pragma unroll
    for (int off = 32; off; off >>= 1) rs += __shfl_xor(rs, off);
    if (lane == 0) {
        rsum[row] = rs;
        rcnt[row] = min(base, 64);
    }
}

// edge bucketing + perm normalization (flags come from k_pre, prior launch)
__device__ __forceinline__ void prep_body(int idx,
                                          const unsigned* __restrict__ eraw,
                                          const unsigned* __restrict__ praw,
                                          const int* __restrict__ flags,
                                          int* __restrict__ perm32,
                                          int* __restrict__ cnt,
                                          int* __restrict__ adj, int E, int n) {
    if (idx < E) {
        int f = flags[0];
        unsigned s = f ? eraw[2 * (size_t)idx] : eraw[idx];
        unsigned d = f ? eraw[2 * (size_t)(E + idx)] : eraw[E + idx];
        int si = (int)(s & (unsigned)NMASK);
        int di = (int)(d & (unsigned)NMASK);
        int p = atomicAdd(&cnt[di], 1);
        if (p < 64) adj[(di << 6) | p] = si;
    } else {
        int j = idx - E;
        if (j < n) {
            unsigned v = flags[1] ? praw[2 * (size_t)j] : praw[j];
            perm32[j] = (int)(v & (unsigned)NMASK);
        }
    }
}

// gemm1 (MFMA-bound) + mask scan (HBM-bound) + prep, disjoint block families:
// the scan's 268MB stream hides under gemm1's MFMA time (max, not sum — m114).
__global__ __launch_bounds__(256) void k_mega(const float* __restrict__ gene,
                                              const __hip_bfloat16* __restrict__ W1t,
                                              unsigned short* __restrict__ xw1b,
                                              const float* __restrict__ mask,
                                              uint2* __restrict__ ents_g,
                                              float* __restrict__ rsum,
                                              int* __restrict__ rcnt,
                                              const unsigned* __restrict__ eraw,
                                              const unsigned* __restrict__ praw,
                                              const int* __restrict__ flags,
                                              int* __restrict__ perm32,
                                              int* __restrict__ cnt,
                                              int* __restrict__ adj, int E, int n) {
    __shared__ __align__(16) char smem[32768];
    int b = blockIdx.x;
    if (b < GB) {
        gemm1_body(smem, b, gene, W1t, xw1b);
    } else if (b < GB + SB) {
        scan_body(smem, b - GB, mask, ents_g, rsum, rcnt, n);
    } else {
        prep_body((b - GB - SB) * 256 + threadIdx.x, eraw, praw, flags,
                  perm32, cnt, adj, E, n);
    }
}

// ---------------- GCN aggregation layer 1 (bf16 xw1, 256 cols, both graphs) ----------------

__global__ __launch_bounds__(256) void k_agg1(const __hip_bfloat16* __restrict__ xw1,
                                              const int* __restrict__ cnt,
                                              const int* __restrict__ adj,
                                              const int* __restrict__ perm,
                                              const float* __restrict__ b1,
                                              __hip_bfloat16* __restrict__ h_all, int n) {
    int lane = threadIdx.x & 63;
    int i = blockIdx.x * 4 + (threadIdx.x >> 6);
    int ci = cnt[i];
    float di = rsqrtf((float)(1 + ci));
    int pi = perm[i];
    float sw = di * di;
    int c4 = lane * 4;
    floatx4 acc = sw * b4f(xw1 + (size_t)i * H1 + c4);
    floatx4 accc = sw * b4f(xw1 + (size_t)pi * H1 + c4);
    int e = min(ci, 64);
    const int* arow = adj + ((size_t)i << 6);
#pragma unroll 4
    for (int t = 0; t < e; ++t) {
        int j = arow[t];
        float wv = di * rsqrtf((float)(1 + cnt[j]));
        int pj = perm[j];
        acc += wv * b4f(xw1 + (size_t)j * H1 + c4);
        accc += wv * b4f(xw1 + (size_t)pj * H1 + c4);
    }
    floatx4 b4 = *reinterpret_cast<const floatx4*>(b1 + c4);
    ushort4 h0, h1;
    h0.x = f2b(fmaxf(acc[0] + b4[0], 0.f));
    h0.y = f2b(fmaxf(acc[1] + b4[1], 0.f));
    h0.z = f2b(fmaxf(acc[2] + b4[2], 0.f));
    h0.w = f2b(fmaxf(acc[3] + b4[3], 0.f));
    h1.x = f2b(fmaxf(accc[0] + b4[0], 0.f));
    h1.y = f2b(fmaxf(accc[1] + b4[1], 0.f));
    h1.z = f2b(fmaxf(accc[2] + b4[2], 0.f));
    h1.w = f2b(fmaxf(accc[3] + b4[3], 0.f));
    *reinterpret_cast<ushort4*>(h_all + (size_t)i * H1 + c4) = h0;
    *reinterpret_cast<ushort4*>(h_all + (size_t)(n + i) * H1 + c4) = h1;
}

// ---------------- GEMM2: hw_all = h_all(bf16) @ W2, BM=64 BN=64 BK=32, reg-prefetch ----------------

__global__ __launch_bounds__(256) void k_gemm2(const __hip_bfloat16* __restrict__ A,
                                               const __hip_bfloat16* __restrict__ Bt,
                                               float* __restrict__ C,
                                               int M, int N, int K) {
    __shared__ __align__(16) unsigned short As[64 * 40];
    __shared__ __align__(16) unsigned short Bs[64 * 40];
    int t = threadIdx.x;
    int m0 = blockIdx.x * 64;
    int n0 = blockIdx.y * 64;
    int lane = t & 63;
    int w = t >> 6;
    int srow = t >> 2;
    int schunk = (t & 3) * 8;
    size_t aoff = (size_t)(m0 + srow) * K + schunk;
    const unsigned short* Brow = (const unsigned short*)Bt + (size_t)(n0 + srow) * K + schunk;

    floatx4 acc0 = {0.f, 0.f, 0.f, 0.f}, acc1 = acc0, acc2 = acc0, acc3 = acc0;
    int msub = w * 16;
    int arow = msub + (lane & 15);
    int koff = (lane >> 4) * 8;
    int nlo = lane & 15;

    uint4 pa = *reinterpret_cast<const uint4*>((const unsigned short*)A + aoff);
    uint4 pb = *reinterpret_cast<const uint4*>(Brow);
    for (int k0 = 0; k0 < K; k0 += 32) {
        uint4 av = pa, bv = pb;
        __syncthreads();
        *reinterpret_cast<uint4*>(&As[srow * 40 + schunk]) = av;
        *reinterpret_cast<uint4*>(&Bs[srow * 40 + schunk]) = bv;
        __syncthreads();
        if (k0 + 32 < K) {
            pa = *reinterpret_cast<const uint4*>((const unsigned short*)A + aoff + k0 + 32);
            pb = *reinterpret_cast<const uint4*>(Brow + k0 + 32);
        }
        bf16x8 af = *reinterpret_cast<const bf16x8*>(&As[arow * 40 + koff]);
        bf16x8 bf0 = *reinterpret_cast<const bf16x8*>(&Bs[(0 + nlo) * 40 + koff]);
        bf16x8 bf1 = *reinterpret_cast<const bf16x8*>(&Bs[(16 + nlo) * 40 + koff]);
        bf16x8 bf2 = *reinterpret_cast<const bf16x8*>(&Bs[(32 + nlo) * 40 + koff]);
        bf16x8 bf3 = *reinterpret_cast<const bf16x8*>(&Bs[(48 + nlo) * 40 + koff]);
        acc0 = __builtin_amdgcn_mfma_f32_16x16x32_bf16(af, bf0, acc0, 0, 0, 0);
        acc1 = __builtin_amdgcn_mfma_f32_16x16x32_bf16(af, bf1, acc1, 0, 0, 0);
        acc2 = __builtin_amdgcn_mfma_f32_16x16x32_bf16(af, bf2, acc2, 0, 0, 0);
        acc3 = __builtin_amdgcn_mfma_f32_16x16x32_bf16(af, bf3, acc3, 0, 0, 0);
    }
    int crow = msub + (lane >> 4) * 4;
    int ccol = lane & 15;
    floatx4 accs[4] = {acc0, acc1, acc2, acc3};
#pragma unroll
    for (int j = 0; j < 4; ++j) {
#pragma unroll
        for (int r = 0; r < 4; ++r) {
            C[(size_t)(m0 + crow + r) * N + (n0 + j * 16 + ccol)] = accs[j][r];
        }
    }
}

// ---------------- GCN aggregation layer 2 (64 cols, both graphs, fp32) ----------------

__global__ __launch_bounds__(256) void k_agg2(const float* __restrict__ hw_all,
                                              const int* __restrict__ cnt,
                                              const int* __restrict__ adj,
                                              const float* __restrict__ b2,
                                              float* __restrict__ x1_all,
                                              float* __restrict__ out_x1, int n) {
    int lane = threadIdx.x & 63;
    int i = blockIdx.x * 4 + (threadIdx.x >> 6);
    int ci = cnt[i];
    float di = rsqrtf((float)(1 + ci));
    float sw = di * di;
    float acc = sw * hw_all[(size_t)i * OUTD + lane];
    float accc = sw * hw_all[(size_t)(n + i) * OUTD + lane];
    int e = min(ci, 64);
    const int* arow = adj + ((size_t)i << 6);
#pragma unroll 4
    for (int t = 0; t < e; ++t) {
        int j = arow[t];
        float wv = di * rsqrtf((float)(1 + cnt[j]));
        acc += wv * hw_all[(size_t)j * OUTD + lane];
        accc += wv * hw_all[(size_t)(n + j) * OUTD + lane];
    }
    float b = b2[lane];
    float v = fmaxf(acc + b, 0.f);
    float vc = fmaxf(accc + b, 0.f);
    x1_all[(size_t)i * OUTD + lane] = v;
    x1_all[(size_t)(n + i) * OUTD + lane] = vc;
    out_x1[(size_t)i * OUTD + lane] = v;
}

// ---------------- finish: entry gathers + mean + L2-norm + sigmoid + bilinear ----------------

__global__ __launch_bounds__(256) void k_finish(const float* __restrict__ x1_all,
                                                const uint2* __restrict__ ents_g,
                                                const float* __restrict__ rsum,
                                                const int* __restrict__ rcnt,
                                                const float* __restrict__ Wd,
                                                const float* __restrict__ bd,
                                                float* __restrict__ ret1,
                                                float* __restrict__ ret1c, int n) {
    int lane = threadIdx.x & 63;
    int w = threadIdx.x >> 6;
    int row = blockIdx.x * 4 + w;
    int cnt = rcnt[row];
    float rs = rsum[row];
    const uint2* erow = ents_g + ((size_t)row << 6);
    float acc = 0.f, accc = 0.f;
#pragma unroll 2
    for (int e = 0; e < cnt; ++e) {
        uint2 ent = erow[e];              // wave-uniform broadcast read
        float m = __uint_as_float(ent.y);
        int j = (int)ent.x;
        acc += m * x1_all[(size_t)j * OUTD + lane];
        accc += m * x1_all[(size_t)(n + j) * OUTD + lane];
    }
    float rst = fmaxf(rs, 1e-20f);
    float g = acc / rst;
    float gc = accc / rst;
    float s1 = g * g, s2 = gc * gc;
#pragma unroll
    for (int off = 32; off; off >>= 1) {
        s1 += __shfl_xor(s1, off);
        s2 += __shfl_xor(s2, off);
    }
    float gn = g / fmaxf(sqrtf(s1), 1e-12f);
    float gnc = gc / fmaxf(sqrtf(s2), 1e-12f);
    float gsig = 1.f / (1.f + __expf(-gn));
    float gcsig = 1.f / (1.f + __expf(-gnc));
    // fused bilinear: tg[lane] = sum_j Wd[lane][j] * g[j] (shfl broadcast)
    float tg = 0.f, tgc = 0.f;
    const float* wrow = Wd + lane * 64;
#pragma unroll 8
    for (int j = 0; j < 64; ++j) {
        float gj = __shfl(gsig, j);
        float gcj = __shfl(gcsig, j);
        float wv = wrow[j];
        tg += wv * gj;
        tgc += wv * gcj;
    }
    float x = x1_all[(size_t)row * OUTD + lane];
    float xc = x1_all[(size_t)(n + row) * OUTD + lane];
    float r0 = x * tg, r1 = xc * tg, r2 = xc * tgc, r3 = x * tgc;
#pragma unroll
    for (int off = 32; off; off >>= 1) {
        r0 += __shfl_down(r0, off);
        r1 += __shfl_down(r1, off);
        r2 += __shfl_down(r2, off);
        r3 += __shfl_down(r3, off);
    }
    if (lane == 0) {
        float b = bd[0];
        ret1[(size_t)row * 2 + 0] = r0 + b;
        ret1[(size_t)row * 2 + 1] = r1 + b;
        ret1c[(size_t)row * 2 + 0] = r2 + b;
        ret1c[(size_t)row * 2 + 1] = r3 + b;
    }
}

// ---------------- host ----------------

extern "C" void kernel_launch(void* const* d_in, const int* in_sizes, int n_in,
                              void* d_out, int out_size, void* d_ws, size_t ws_size,
                              hipStream_t stream) {
    const float* gene = (const float*)d_in[0];
    const float* mask = (const float*)d_in[1];
    const float* W1 = (const float*)d_in[2];
    const float* b1 = (const float*)d_in[3];
    const float* W2 = (const float*)d_in[4];
    const float* b2 = (const float*)d_in[5];
    const float* Wd = (const float*)d_in[6];
    const float* bd = (const float*)d_in[7];
    const unsigned* eidx_raw = (const unsigned*)d_in[8];
    const unsigned* perm_raw = (const unsigned*)d_in[9];
    const int n = NN;
    const int E = in_sizes[8] / 2;  // 131072 logical edge count

    // workspace carve-up (256B aligned); peak ~19.8 MB
    char* base = (char*)d_ws;
    char* p = base;
    auto alloc = [&](size_t bytes) -> char* {
        char* r = p;
        p += (bytes + 255) & ~(size_t)255;
        return r;
    };
    int* flags = (int*)alloc(256);
    int* cnt = (int*)alloc((size_t)n * 4);
    int* adj = (int*)alloc((size_t)n * 64 * 4);                            // 2 MB
    int* perm32 = (int*)alloc((size_t)n * 4);
    uint2* ents_g = (uint2*)alloc((size_t)n * 64 * 8);                     // 4 MB
    float* rsum = (float*)alloc((size_t)n * 4);
    int* rcnt = (int*)alloc((size_t)n * 4);
    __hip_bfloat16* W2t = (__hip_bfloat16*)alloc((size_t)H1 * OUTD * 2);
    __hip_bfloat16* W1t = (__hip_bfloat16*)alloc((size_t)INDP * H1 * 2);   // padded ld
    __hip_bfloat16* xw1b = (__hip_bfloat16*)alloc((size_t)n * H1 * 2);     // 4 MB
    __hip_bfloat16* h_all = (__hip_bfloat16*)alloc((size_t)2 * n * H1 * 2);// 8 MB
    size_t need = (size_t)(p - base);
    // aliases into dead buffers:
    float* hw_all = (float*)xw1b;   // 2n*64 fp32 = 4 MB (xw1b dead after agg1)
    float* x1_all = (float*)h_all;  // 2n*64 fp32 = 4 MB (h_all dead after gemm2)

    float* out_x1 = (float*)d_out;
    float* out_ret1 = out_x1 + (size_t)n * OUTD;
    float* out_ret1c = out_ret1 + (size_t)n * 2;

    if (ws_size < need) {
        k_probe<<<1, 64, 0, stream>>>(1000.f + (float)(ws_size >> 20), out_x1);
        return;
    }

    hipMemsetAsync(cnt, 0, (size_t)n * 4, stream);

    // 0. pre-pass: detect widths, zero W1t pad, transposes (grid 4 + 3064)
    k_pre<<<4 + (IND * H1 + H1 * OUTD + 255) / 256, 256, 0, stream>>>(
        eidx_raw, perm_raw, flags, W1, W2, W1t, W2t);

    // 1. mega: gemm1 (MFMA) + mask scan (HBM) + edge bucketing, concurrent families
    k_mega<<<GB + SB + PB, 256, 0, stream>>>(gene, W1t, (unsigned short*)xw1b,
                                             mask, ents_g, rsum, rcnt,
                                             eidx_raw, perm_raw, flags,
                                             perm32, cnt, adj, E, n);

    // 2. conv1 aggregation (both graphs) -> h_all bf16 [2n x 256]
    k_agg1<<<n / 4, 256, 0, stream>>>(xw1b, cnt, adj, perm32, b1, h_all, n);

    // 3. GEMM2: hw_all = h_all(bf16) @ W2  (writes into dead xw1b region)
    k_gemm2<<<dim3(2 * n / 64, OUTD / 64), 256, 0, stream>>>(h_all, W2t, hw_all, 2 * n, OUTD, H1);

    // 4. conv2 aggregation -> x1_all fp32 [2n x 64]; x1 also to d_out
    k_agg2<<<n / 4, 256, 0, stream>>>(hw_all, cnt, adj, b2, x1_all, out_x1, n);

    // 5. finish: entry gathers + mean/norm/sigmoid + bilinear -> ret1, ret1_c
    k_finish<<<n / 4, 256, 0, stream>>>(x1_all, ents_g, rsum, rcnt, Wd, bd,
                                        out_ret1, out_ret1c, n);
}

// Round 7
// 543.793 us; speedup vs baseline: 5.1130x; 1.0030x over previous
//
#include <hip/hip_runtime.h>
#include <hip/hip_bf16.h>

// Problem constants (fixed by reference)
#define NN 8192
#define NMASK 8191
#define IND 3000
#define INDP 3008   // padded K for W1t rows: 3008*2B = 6016 bytes, 16B-aligned rows
#define H1 256
#define OUTD 64

// mega-kernel block families
#define GB 512      // gemm1 blocks (4 n-panels x 128 m-panels)
#define SB 2048     // mask-scan blocks (4 rows each)
#define PB 544      // prep blocks ((131072 + 8192)/256)

typedef __bf16 bf16x8 __attribute__((ext_vector_type(8)));
typedef float floatx4 __attribute__((ext_vector_type(4)));

typedef const __attribute__((address_space(1))) void GV;
typedef __attribute__((address_space(3))) void LV;

__device__ __forceinline__ unsigned short f2b(float f) {
    __hip_bfloat16 h = __float2bfloat16(f);
    unsigned short u;
    __builtin_memcpy(&u, &h, 2);
    return u;
}

// bf16x4 -> fp32x4 (bf16 is truncated fp32: shift<<16)
__device__ __forceinline__ floatx4 b4f(const __hip_bfloat16* p) {
    ushort4 u = *reinterpret_cast<const ushort4*>(p);
    floatx4 r;
    r[0] = __uint_as_float((unsigned)u.x << 16);
    r[1] = __uint_as_float((unsigned)u.y << 16);
    r[2] = __uint_as_float((unsigned)u.z << 16);
    r[3] = __uint_as_float((unsigned)u.w << 16);
    return r;
}

// ---------------- ws-size probe ----------------

__global__ void k_probe(float code, float* out) {
    if (threadIdx.x == 0 && blockIdx.x == 0) out[0] = code;
}

// ---------------- pre-pass: detect widths, zero W1t pad, weight transposes ----------------

__global__ void k_pre(const unsigned* __restrict__ eraw, const unsigned* __restrict__ praw,
                      int* __restrict__ flags,
                      const float* __restrict__ W1, const float* __restrict__ W2,
                      __hip_bfloat16* __restrict__ W1t, __hip_bfloat16* __restrict__ W2t) {
    int b = blockIdx.x;
    int t = threadIdx.x;
    if (b < 2) {
        const unsigned* r = (b == 0) ? eraw : praw;
        __shared__ int c;
        if (t == 0) c = 0;
        __syncthreads();
        int z = 0;
        for (int k = t; k < 2048; k += 256)
            if (r[2 * k + 1] == 0u) z++;
        atomicAdd(&c, z);
        __syncthreads();
        if (t == 0) flags[b] = (c > 1024) ? 1 : 0;
    } else if (b < 4) {
        int idx = (b - 2) * 256 + t;  // 0..511, each covers 4 pad elems
#pragma unroll
        for (int u = 0; u < 4; ++u) {
            int k = idx * 4 + u;      // 0..2047 = 8 pad rows x 256 cols
            int c = k >> 3;
            int r = 3000 + (k & 7);
            W1t[(size_t)c * INDP + r] = __float2bfloat16(0.f);
        }
    } else {
        int idx = (b - 4) * 256 + t;
        if (idx < IND * H1) {
            int r = idx / H1, c = idx % H1;
            W1t[(size_t)c * INDP + r] = __float2bfloat16(W1[idx]);
        } else {
            int j = idx - IND * H1;
            if (j < H1 * OUTD) {
                int r = j / OUTD, c = j % OUTD;
                W2t[(size_t)c * H1 + r] = __float2bfloat16(W2[j]);
            }
        }
    }
}

// ---------------- mega-kernel bodies ----------------

// GEMM1: xw1(bf16)[8192][256] = gene(fp32) @ W1. BM=64 BN=64 BK=64, reg-prefetch.
__device__ __forceinline__ void gemm1_body(char* smem, int blk,
                                           const float* __restrict__ A,
                                           const __hip_bfloat16* __restrict__ Bt,
                                           unsigned short* __restrict__ C) {
    unsigned short* As = (unsigned short*)smem;           // 64*72*2 = 9216 B
    unsigned short* Bs = As + 64 * 72;                    // +9216 B (18.4 KB total)
    int t = threadIdx.x;
    int n0 = (blk & 3) * 64;   // 4 consecutive blocks share one A panel
    int m0 = (blk >> 2) * 64;
    int lane = t & 63;
    int w = t >> 6;
    int srow = t >> 2;
    int schunk = (t & 3) * 16;
    const float* Arow = A + (size_t)(m0 + srow) * IND + schunk;
    const unsigned short* Brow = (const unsigned short*)Bt + (size_t)(n0 + srow) * INDP + schunk;

    floatx4 acc0 = {0.f, 0.f, 0.f, 0.f}, acc1 = acc0, acc2 = acc0, acc3 = acc0;
    int msub = w * 16;
    int arow = msub + (lane & 15);
    int koff = (lane >> 4) * 8;
    int nlo = lane & 15;

    float4 pa0, pa1, pa2, pa3;
    uint4 pb0, pb1;
    auto load_tile = [&](int k0) {
        float4 z4 = make_float4(0.f, 0.f, 0.f, 0.f);
        uint4 zu = make_uint4(0u, 0u, 0u, 0u);
        pa0 = z4; pa1 = z4; pa2 = z4; pa3 = z4; pb0 = zu; pb1 = zu;
        int kk = k0 + schunk;
        if (kk < IND) {
            const float* ap = Arow + k0;
            pa0 = *reinterpret_cast<const float4*>(ap);
            pa1 = *reinterpret_cast<const float4*>(ap + 4);
            pb0 = *reinterpret_cast<const uint4*>(Brow + k0);
        }
        if (kk + 8 < IND) {
            const float* ap = Arow + k0 + 8;
            pa2 = *reinterpret_cast<const float4*>(ap);
            pa3 = *reinterpret_cast<const float4*>(ap + 4);
            pb1 = *reinterpret_cast<const uint4*>(Brow + k0 + 8);
        }
    };
    load_tile(0);
    for (int k0 = 0; k0 < IND; k0 += 64) {
        uint4 av0, av1, bv0 = pb0, bv1 = pb1;
        {
            unsigned short t8[8] = {f2b(pa0.x), f2b(pa0.y), f2b(pa0.z), f2b(pa0.w),
                                    f2b(pa1.x), f2b(pa1.y), f2b(pa1.z), f2b(pa1.w)};
            __builtin_memcpy(&av0, t8, 16);
        }
        {
            unsigned short t8[8] = {f2b(pa2.x), f2b(pa2.y), f2b(pa2.z), f2b(pa2.w),
                                    f2b(pa3.x), f2b(pa3.y), f2b(pa3.z), f2b(pa3.w)};
            __builtin_memcpy(&av1, t8, 16);
        }
        __syncthreads();
        *reinterpret_cast<uint4*>(&As[srow * 72 + schunk]) = av0;
        *reinterpret_cast<uint4*>(&As[srow * 72 + schunk + 8]) = av1;
        *reinterpret_cast<uint4*>(&Bs[srow * 72 + schunk]) = bv0;
        *reinterpret_cast<uint4*>(&Bs[srow * 72 + schunk + 8]) = bv1;
        __syncthreads();
        if (k0 + 64 < IND) load_tile(k0 + 64);
#pragma unroll
        for (int ks = 0; ks < 64; ks += 32) {
            bf16x8 af = *reinterpret_cast<const bf16x8*>(&As[arow * 72 + ks + koff]);
            bf16x8 b0 = *reinterpret_cast<const bf16x8*>(&Bs[(0 + nlo) * 72 + ks + koff]);
            bf16x8 b1 = *reinterpret_cast<const bf16x8*>(&Bs[(16 + nlo) * 72 + ks + koff]);
            bf16x8 b2 = *reinterpret_cast<const bf16x8*>(&Bs[(32 + nlo) * 72 + ks + koff]);
            bf16x8 b3 = *reinterpret_cast<const bf16x8*>(&Bs[(48 + nlo) * 72 + ks + koff]);
            acc0 = __builtin_amdgcn_mfma_f32_16x16x32_bf16(af, b0, acc0, 0, 0, 0);
            acc1 = __builtin_amdgcn_mfma_f32_16x16x32_bf16(af, b1, acc1, 0, 0, 0);
            acc2 = __builtin_amdgcn_mfma_f32_16x16x32_bf16(af, b2, acc2, 0, 0, 0);
            acc3 = __builtin_amdgcn_mfma_f32_16x16x32_bf16(af, b3, acc3, 0, 0, 0);
        }
    }
    // C/D layout: col = lane&15, row = (lane>>4)*4 + r   [verified m89/m91]
    int crow = msub + (lane >> 4) * 4;
    int ccol = lane & 15;
    floatx4 accs[4] = {acc0, acc1, acc2, acc3};
#pragma unroll
    for (int j = 0; j < 4; ++j) {
#pragma unroll
        for (int r = 0; r < 4; ++r) {
            C[(size_t)(m0 + crow + r) * H1 + (n0 + j * 16 + ccol)] = f2b(accs[j][r]);
        }
    }
}

// mask scan with PER-ROW CHUNK-PHASE ROTATION.
// All mask rows are exactly 32KB (power-of-2). Row-owning waves marching in
// lockstep put the instantaneous address set on ~4 distinct residues mod the
// HBM channel-interleave period -> channel/bank camping -> ~2.2TB/s (R6 PMC:
// 27% HBM, 3% MFMA, 8% VALU, all idle). Rotating each row's chunk start phase
// spreads concurrent addresses across the full period.
__device__ __forceinline__ void scan_body(char* smem, int blk,
                                          const float* __restrict__ mask,
                                          uint2* __restrict__ ents_g,
                                          float* __restrict__ rsum,
                                          int* __restrict__ rcnt, int n) {
    float (*ring)[4][512] = reinterpret_cast<float (*)[4][512]>(smem);  // 32 KB
    int lane = threadIdx.x & 63;
    int w = threadIdx.x >> 6;
    int row = blk * 4 + w;
    int phase = (row + (row >> 2) + (row >> 4)) & 15;   // decorrelate vs row base
    const float* mrow = mask + (size_t)row * n;
    uint2* erow = ents_g + ((size_t)row << 6);

    auto issue = [&](int k) {
        int slot = k & 3;
        int c = (phase + k) & 15;
        const float* g0 = mrow + c * 512 + lane * 4;
        __builtin_amdgcn_global_load_lds((GV*)g0, (LV*)&ring[w][slot][0], 16, 0, 0);
        __builtin_amdgcn_global_load_lds((GV*)(g0 + 256), (LV*)&ring[w][slot][256], 16, 0, 0);
    };
    issue(0);
    issue(1);
    issue(2);

    int base = 0;      // wave-uniform running entry count
    float rs = 0.f;    // per-lane partial row sum
    unsigned long long below = (lane == 63) ? ~0ull >> 1 : (1ull << lane) - 1;
    for (int k = 0; k < 16; ++k) {
        if (k < 13) {
            issue(k + 3);
            asm volatile("s_waitcnt vmcnt(6)" ::: "memory");
        } else if (k == 13) {
            asm volatile("s_waitcnt vmcnt(4)" ::: "memory");
        } else if (k == 14) {
            asm volatile("s_waitcnt vmcnt(2)" ::: "memory");
        } else {
            asm volatile("s_waitcnt vmcnt(0)" ::: "memory");
        }
        int slot = k & 3;
        int c = (phase + k) & 15;
        floatx4 q0 = *reinterpret_cast<floatx4*>(&ring[w][slot][lane * 4]);
        floatx4 q1 = *reinterpret_cast<floatx4*>(&ring[w][slot][256 + lane * 4]);
        int cb = c * 512 + lane * 4;
#pragma unroll
        for (int u = 0; u < 4; ++u) {
            float v = q0[u];
            unsigned long long bal = __ballot(v != 0.f);
            if (v != 0.f) {
                int r = base + __popcll(bal & below);
                if (r < 64) erow[r] = make_uint2((unsigned)(cb + u), __float_as_uint(v));
                rs += v;
            }
            base += __popcll(bal);
        }
#pragma unroll
        for (int u = 0; u < 4; ++u) {
            float v = q1[u];
            unsigned long long bal = __ballot(v != 0.f);
            if (v != 0.f) {
                int r = base + __popcll(bal & below);
                if (r < 64) erow[r] = make_uint2((unsigned)(cb + 256 + u), __float_as_uint(v));
                rs += v;
            }
            base += __popcll(bal);
        }
    }
#pragma unroll
    for (int off = 32; off; off >>= 1) rs += __shfl_xor(rs, off);
    if (lane == 0) {
        rsum[row] = rs;
        rcnt[row] = min(base, 64);
    }
}

// edge bucketing + perm normalization (flags come from k_pre, prior launch)
__device__ __forceinline__ void prep_body(int idx,
                                          const unsigned* __restrict__ eraw,
                                          const unsigned* __restrict__ praw,
                                          const int* __restrict__ flags,
                                          int* __restrict__ perm32,
                                          int* __restrict__ cnt,
                                          int* __restrict__ adj, int E, int n) {
    if (idx < E) {
        int f = flags[0];
        unsigned s = f ? eraw[2 * (size_t)idx] : eraw[idx];
        unsigned d = f ? eraw[2 * (size_t)(E + idx)] : eraw[E + idx];
        int si = (int)(s & (unsigned)NMASK);
        int di = (int)(d & (unsigned)NMASK);
        int p = atomicAdd(&cnt[di], 1);
        if (p < 64) adj[(di << 6) | p] = si;
    } else {
        int j = idx - E;
        if (j < n) {
            unsigned v = flags[1] ? praw[2 * (size_t)j] : praw[j];
            perm32[j] = (int)(v & (unsigned)NMASK);
        }
    }
}

// gemm1 (MFMA-bound) + mask scan (HBM-bound) + prep, disjoint block families
__global__ __launch_bounds__(256) void k_mega(const float* __restrict__ gene,
                                              const __hip_bfloat16* __restrict__ W1t,
                                              unsigned short* __restrict__ xw1b,
                                              const float* __restrict__ mask,
                                              uint2* __restrict__ ents_g,
                                              float* __restrict__ rsum,
                                              int* __restrict__ rcnt,
                                              const unsigned* __restrict__ eraw,
                                              const unsigned* __restrict__ praw,
                                              const int* __restrict__ flags,
                                              int* __restrict__ perm32,
                                              int* __restrict__ cnt,
                                              int* __restrict__ adj, int E, int n) {
    __shared__ __align__(16) char smem[32768];
    int b = blockIdx.x;
    if (b < GB) {
        gemm1_body(smem, b, gene, W1t, xw1b);
    } else if (b < GB + SB) {
        scan_body(smem, b - GB, mask, ents_g, rsum, rcnt, n);
    } else {
        prep_body((b - GB - SB) * 256 + threadIdx.x, eraw, praw, flags,
                  perm32, cnt, adj, E, n);
    }
}

// ---------------- GCN aggregation layer 1 (bf16 xw1, 256 cols, both graphs) ----------------

__global__ __launch_bounds__(256) void k_agg1(const __hip_bfloat16* __restrict__ xw1,
                                              const int* __restrict__ cnt,
                                              const int* __restrict__ adj,
                                              const int* __restrict__ perm,
                                              const float* __restrict__ b1,
                                              __hip_bfloat16* __restrict__ h_all, int n) {
    int lane = threadIdx.x & 63;
    int i = blockIdx.x * 4 + (threadIdx.x >> 6);
    int ci = cnt[i];
    float di = rsqrtf((float)(1 + ci));
    int pi = perm[i];
    float sw = di * di;
    int c4 = lane * 4;
    floatx4 acc = sw * b4f(xw1 + (size_t)i * H1 + c4);
    floatx4 accc = sw * b4f(xw1 + (size_t)pi * H1 + c4);
    int e = min(ci, 64);
    const int* arow = adj + ((size_t)i << 6);
#pragma unroll 4
    for (int t = 0; t < e; ++t) {
        int j = arow[t];
        float wv = di * rsqrtf((float)(1 + cnt[j]));
        int pj = perm[j];
        acc += wv * b4f(xw1 + (size_t)j * H1 + c4);
        accc += wv * b4f(xw1 + (size_t)pj * H1 + c4);
    }
    floatx4 b4 = *reinterpret_cast<const floatx4*>(b1 + c4);
    ushort4 h0, h1;
    h0.x = f2b(fmaxf(acc[0] + b4[0], 0.f));
    h0.y = f2b(fmaxf(acc[1] + b4[1], 0.f));
    h0.z = f2b(fmaxf(acc[2] + b4[2], 0.f));
    h0.w = f2b(fmaxf(acc[3] + b4[3], 0.f));
    h1.x = f2b(fmaxf(accc[0] + b4[0], 0.f));
    h1.y = f2b(fmaxf(accc[1] + b4[1], 0.f));
    h1.z = f2b(fmaxf(accc[2] + b4[2], 0.f));
    h1.w = f2b(fmaxf(accc[3] + b4[3], 0.f));
    *reinterpret_cast<ushort4*>(h_all + (size_t)i * H1 + c4) = h0;
    *reinterpret_cast<ushort4*>(h_all + (size_t)(n + i) * H1 + c4) = h1;
}

// ---------------- GEMM2: hw_all = h_all(bf16) @ W2, BM=64 BN=64 BK=32, reg-prefetch ----------------

__global__ __launch_bounds__(256) void k_gemm2(const __hip_bfloat16* __restrict__ A,
                                               const __hip_bfloat16* __restrict__ Bt,
                                               float* __restrict__ C,
                                               int M, int N, int K) {
    __shared__ __align__(16) unsigned short As[64 * 40];
    __shared__ __align__(16) unsigned short Bs[64 * 40];
    int t = threadIdx.x;
    int m0 = blockIdx.x * 64;
    int n0 = blockIdx.y * 64;
    int lane = t & 63;
    int w = t >> 6;
    int srow = t >> 2;
    int schunk = (t & 3) * 8;
    size_t aoff = (size_t)(m0 + srow) * K + schunk;
    const unsigned short* Brow = (const unsigned short*)Bt + (size_t)(n0 + srow) * K + schunk;

    floatx4 acc0 = {0.f, 0.f, 0.f, 0.f}, acc1 = acc0, acc2 = acc0, acc3 = acc0;
    int msub = w * 16;
    int arow = msub + (lane & 15);
    int koff = (lane >> 4) * 8;
    int nlo = lane & 15;

    uint4 pa = *reinterpret_cast<const uint4*>((const unsigned short*)A + aoff);
    uint4 pb = *reinterpret_cast<const uint4*>(Brow);
    for (int k0 = 0; k0 < K; k0 += 32) {
        uint4 av = pa, bv = pb;
        __syncthreads();
        *reinterpret_cast<uint4*>(&As[srow * 40 + schunk]) = av;
        *reinterpret_cast<uint4*>(&Bs[srow * 40 + schunk]) = bv;
        __syncthreads();
        if (k0 + 32 < K) {
            pa = *reinterpret_cast<const uint4*>((const unsigned short*)A + aoff + k0 + 32);
            pb = *reinterpret_cast<const uint4*>(Brow + k0 + 32);
        }
        bf16x8 af = *reinterpret_cast<const bf16x8*>(&As[arow * 40 + koff]);
        bf16x8 bf0 = *reinterpret_cast<const bf16x8*>(&Bs[(0 + nlo) * 40 + koff]);
        bf16x8 bf1 = *reinterpret_cast<const bf16x8*>(&Bs[(16 + nlo) * 40 + koff]);
        bf16x8 bf2 = *reinterpret_cast<const bf16x8*>(&Bs[(32 + nlo) * 40 + koff]);
        bf16x8 bf3 = *reinterpret_cast<const bf16x8*>(&Bs[(48 + nlo) * 40 + koff]);
        acc0 = __builtin_amdgcn_mfma_f32_16x16x32_bf16(af, bf0, acc0, 0, 0, 0);
        acc1 = __builtin_amdgcn_mfma_f32_16x16x32_bf16(af, bf1, acc1, 0, 0, 0);
        acc2 = __builtin_amdgcn_mfma_f32_16x16x32_bf16(af, bf2, acc2, 0, 0, 0);
        acc3 = __builtin_amdgcn_mfma_f32_16x16x32_bf16(af, bf3, acc3, 0, 0, 0);
    }
    int crow = msub + (lane >> 4) * 4;
    int ccol = lane & 15;
    floatx4 accs[4] = {acc0, acc1, acc2, acc3};
#pragma unroll
    for (int j = 0; j < 4; ++j) {
#pragma unroll
        for (int r = 0; r < 4; ++r) {
            C[(size_t)(m0 + crow + r) * N + (n0 + j * 16 + ccol)] = accs[j][r];
        }
    }
}

// ---------------- GCN aggregation layer 2 (64 cols, both graphs, fp32) ----------------

__global__ __launch_bounds__(256) void k_agg2(const float* __restrict__ hw_all,
                                              const int* __restrict__ cnt,
                                              const int* __restrict__ adj,
                                              const float* __restrict__ b2,
                                              float* __restrict__ x1_all,
                                              float* __restrict__ out_x1, int n) {
    int lane = threadIdx.x & 63;
    int i = blockIdx.x * 4 + (threadIdx.x >> 6);
    int ci = cnt[i];
    float di = rsqrtf((float)(1 + ci));
    float sw = di * di;
    float acc = sw * hw_all[(size_t)i * OUTD + lane];
    float accc = sw * hw_all[(size_t)(n + i) * OUTD + lane];
    int e = min(ci, 64);
    const int* arow = adj + ((size_t)i << 6);
#pragma unroll 4
    for (int t = 0; t < e; ++t) {
        int j = arow[t];
        float wv = di * rsqrtf((float)(1 + cnt[j]));
        acc += wv * hw_all[(size_t)j * OUTD + lane];
        accc += wv * hw_all[(size_t)(n + j) * OUTD + lane];
    }
    float b = b2[lane];
    float v = fmaxf(acc + b, 0.f);
    float vc = fmaxf(accc + b, 0.f);
    x1_all[(size_t)i * OUTD + lane] = v;
    x1_all[(size_t)(n + i) * OUTD + lane] = vc;
    out_x1[(size_t)i * OUTD + lane] = v;
}

// ---------------- finish: entry gathers + mean + L2-norm + sigmoid + bilinear ----------------

__global__ __launch_bounds__(256) void k_finish(const float* __restrict__ x1_all,
                                                const uint2* __restrict__ ents_g,
                                                const float* __restrict__ rsum,
                                                const int* __restrict__ rcnt,
                                                const float* __restrict__ Wd,
                                                const float* __restrict__ bd,
                                                float* __restrict__ ret1,
                                                float* __restrict__ ret1c, int n) {
    int lane = threadIdx.x & 63;
    int w = threadIdx.x >> 6;
    int row = blockIdx.x * 4 + w;
    int cnt = rcnt[row];
    float rs = rsum[row];
    const uint2* erow = ents_g + ((size_t)row << 6);
    float acc = 0.f, accc = 0.f;
#pragma unroll 2
    for (int e = 0; e < cnt; ++e) {
        uint2 ent = erow[e];              // wave-uniform broadcast read
        float m = __uint_as_float(ent.y);
        int j = (int)ent.x;
        acc += m * x1_all[(size_t)j * OUTD + lane];
        accc += m * x1_all[(size_t)(n + j) * OUTD + lane];
    }
    float rst = fmaxf(rs, 1e-20f);
    float g = acc / rst;
    float gc = accc / rst;
    float s1 = g * g, s2 = gc * gc;
#pragma unroll
    for (int off = 32; off; off >>= 1) {
        s1 += __shfl_xor(s1, off);
        s2 += __shfl_xor(s2, off);
    }
    float gn = g / fmaxf(sqrtf(s1), 1e-12f);
    float gnc = gc / fmaxf(sqrtf(s2), 1e-12f);
    float gsig = 1.f / (1.f + __expf(-gn));
    float gcsig = 1.f / (1.f + __expf(-gnc));
    // fused bilinear: tg[lane] = sum_j Wd[lane][j] * g[j] (shfl broadcast)
    float tg = 0.f, tgc = 0.f;
    const float* wrow = Wd + lane * 64;
#pragma unroll 8
    for (int j = 0; j < 64; ++j) {
        float gj = __shfl(gsig, j);
        float gcj = __shfl(gcsig, j);
        float wv = wrow[j];
        tg += wv * gj;
        tgc += wv * gcj;
    }
    float x = x1_all[(size_t)row * OUTD + lane];
    float xc = x1_all[(size_t)(n + row) * OUTD + lane];
    float r0 = x * tg, r1 = xc * tg, r2 = xc * tgc, r3 = x * tgc;
#pragma unroll
    for (int off = 32; off; off >>= 1) {
        r0 += __shfl_down(r0, off);
        r1 += __shfl_down(r1, off);
        r2 += __shfl_down(r2, off);
        r3 += __shfl_down(r3, off);
    }
    if (lane == 0) {
        float b = bd[0];
        ret1[(size_t)row * 2 + 0] = r0 + b;
        ret1[(size_t)row * 2 + 1] = r1 + b;
        ret1c[(size_t)row * 2 + 0] = r2 + b;
        ret1c[(size_t)row * 2 + 1] = r3 + b;
    }
}

// ---------------- host ----------------

extern "C" void kernel_launch(void* const* d_in, const int* in_sizes, int n_in,
                              void* d_out, int out_size, void* d_ws, size_t ws_size,
                              hipStream_t stream) {
    const float* gene = (const float*)d_in[0];
    const float* mask = (const float*)d_in[1];
    const float* W1 = (const float*)d_in[2];
    const float* b1 = (const float*)d_in[3];
    const float* W2 = (const float*)d_in[4];
    const float* b2 = (const float*)d_in[5];
    const float* Wd = (const float*)d_in[6];
    const float* bd = (const float*)d_in[7];
    const unsigned* eidx_raw = (const unsigned*)d_in[8];
    const unsigned* perm_raw = (const unsigned*)d_in[9];
    const int n = NN;
    const int E = in_sizes[8] / 2;  // 131072 logical edge count

    // workspace carve-up (256B aligned); peak ~19.8 MB
    char* base = (char*)d_ws;
    char* p = base;
    auto alloc = [&](size_t bytes) -> char* {
        char* r = p;
        p += (bytes + 255) & ~(size_t)255;
        return r;
    };
    int* flags = (int*)alloc(256);
    int* cnt = (int*)alloc((size_t)n * 4);
    int* adj = (int*)alloc((size_t)n * 64 * 4);                            // 2 MB
    int* perm32 = (int*)alloc((size_t)n * 4);
    uint2* ents_g = (uint2*)alloc((size_t)n * 64 * 8);                     // 4 MB
    float* rsum = (float*)alloc((size_t)n * 4);
    int* rcnt = (int*)alloc((size_t)n * 4);
    __hip_bfloat16* W2t = (__hip_bfloat16*)alloc((size_t)H1 * OUTD * 2);
    __hip_bfloat16* W1t = (__hip_bfloat16*)alloc((size_t)INDP * H1 * 2);   // padded ld
    __hip_bfloat16* xw1b = (__hip_bfloat16*)alloc((size_t)n * H1 * 2);     // 4 MB
    __hip_bfloat16* h_all = (__hip_bfloat16*)alloc((size_t)2 * n * H1 * 2);// 8 MB
    size_t need = (size_t)(p - base);
    // aliases into dead buffers:
    float* hw_all = (float*)xw1b;   // 2n*64 fp32 = 4 MB (xw1b dead after agg1)
    float* x1_all = (float*)h_all;  // 2n*64 fp32 = 4 MB (h_all dead after gemm2)

    float* out_x1 = (float*)d_out;
    float* out_ret1 = out_x1 + (size_t)n * OUTD;
    float* out_ret1c = out_ret1 + (size_t)n * 2;

    if (ws_size < need) {
        k_probe<<<1, 64, 0, stream>>>(1000.f + (float)(ws_size >> 20), out_x1);
        return;
    }

    hipMemsetAsync(cnt, 0, (size_t)n * 4, stream);

    // 0. pre-pass: detect widths, zero W1t pad, transposes
    k_pre<<<4 + (IND * H1 + H1 * OUTD + 255) / 256, 256, 0, stream>>>(
        eidx_raw, perm_raw, flags, W1, W2, W1t, W2t);

    // 1. mega: gemm1 (MFMA) + phase-rotated mask scan (HBM) + edge bucketing
    k_mega<<<GB + SB + PB, 256, 0, stream>>>(gene, W1t, (unsigned short*)xw1b,
                                             mask, ents_g, rsum, rcnt,
                                             eidx_raw, perm_raw, flags,
                                             perm32, cnt, adj, E, n);

    // 2. conv1 aggregation (both graphs) -> h_all bf16 [2n x 256]
    k_agg1<<<n / 4, 256, 0, stream>>>(xw1b, cnt, adj, perm32, b1, h_all, n);

    // 3. GEMM2: hw_all = h_all(bf16) @ W2  (writes into dead xw1b region)
    k_gemm2<<<dim3(2 * n / 64, OUTD / 64), 256, 0, stream>>>(h_all, W2t, hw_all, 2 * n, OUTD, H1);

    // 4. conv2 aggregation -> x1_all fp32 [2n x 64]; x1 also to d_out
    k_agg2<<<n / 4, 256, 0, stream>>>(hw_all, cnt, adj, b2, x1_all, out_x1, n);

    // 5. finish: entry gathers + mean/norm/sigmoid + bilinear -> ret1, ret1_c
    k_finish<<<n / 4, 256, 0, stream>>>(x1_all, ents_g, rsum, rcnt, Wd, bd,
                                        out_ret1, out_ret1c, n);
}